// Round 1
// baseline (5625.900 us; speedup 1.0000x reference)
//
#include <hip/hip_runtime.h>

#define NN 20000
#define NE 640000
#define NR 8
#define NB 8
#define HID 256
#define KPOI 12
#define KTIME 2880
#define KROAD 128

// ---------------- W[r] = sum_b coef[r,b] * basis[b] ----------------
__global__ __launch_bounds__(256) void make_W(const float* __restrict__ coef,
                                              const float* __restrict__ basis,
                                              float* __restrict__ W) {
  int idx = blockIdx.x * 256 + threadIdx.x;
  if (idx >= NR * HID * HID) return;
  int r = idx / (HID * HID);
  int io = idx - r * (HID * HID);
  float acc = 0.f;
#pragma unroll
  for (int b = 0; b < NB; ++b)
    acc += coef[r * NB + b] * basis[b * HID * HID + io];
  W[idx] = acc;
}

// ---------------- generic tiled f32 GEMM: C = A@B (+bias) ----------------
// A: M x K (lda), B: K x N (ldb), C: M x N (ldc), row-major.
#define BM 64
#define BN 64
#define BK 16
#define PAD 68  // row stride in floats; 68*4B keeps 16B alignment, spreads banks

__global__ __launch_bounds__(256) void sgemm(
    int M, int Nn, int K,
    const float* __restrict__ A, int lda,
    const float* __restrict__ B, int ldb,
    const float* __restrict__ bias,
    float* __restrict__ C, int ldc)
{
  __shared__ float As[BK * PAD];  // transposed: As[k][m]
  __shared__ float Bs[BK * PAD];  // Bs[k][n]
  const int tid = threadIdx.x;
  const int brow = blockIdx.x * BM;
  const int bcol = blockIdx.y * BN;
  const int tm = (tid >> 4) * 4;
  const int tn = (tid & 15) * 4;

  const int arow = tid >> 2;        // 0..63
  const int ak0  = (tid & 3) * 4;   // 0,4,8,12
  const int bk   = tid >> 4;        // 0..15
  const int bn0  = (tid & 15) * 4;  // 0..60

  float acc[4][4] = {};

  for (int kb = 0; kb < K; kb += BK) {
    // ---- load A tile (BM x BK), transposed into As[k][m] ----
    {
      int r0 = brow + arow;
      int k0 = kb + ak0;
      if (r0 < M && k0 + 3 < K) {
        float4 v = *(const float4*)(A + (size_t)r0 * lda + k0);
        As[(ak0 + 0) * PAD + arow] = v.x;
        As[(ak0 + 1) * PAD + arow] = v.y;
        As[(ak0 + 2) * PAD + arow] = v.z;
        As[(ak0 + 3) * PAD + arow] = v.w;
      } else {
#pragma unroll
        for (int i = 0; i < 4; ++i) {
          float v = 0.f;
          if (r0 < M && k0 + i < K) v = A[(size_t)r0 * lda + k0 + i];
          As[(ak0 + i) * PAD + arow] = v;
        }
      }
    }
    // ---- load B tile (BK x BN) into Bs[k][n] ----
    {
      int kr = kb + bk;
      int c0 = bcol + bn0;
      if (kr < K && c0 + 3 < Nn) {
        float4 v = *(const float4*)(B + (size_t)kr * ldb + c0);
        Bs[bk * PAD + bn0 + 0] = v.x;
        Bs[bk * PAD + bn0 + 1] = v.y;
        Bs[bk * PAD + bn0 + 2] = v.z;
        Bs[bk * PAD + bn0 + 3] = v.w;
      } else {
#pragma unroll
        for (int j = 0; j < 4; ++j) {
          float v = 0.f;
          if (kr < K && c0 + j < Nn) v = B[(size_t)kr * ldb + c0 + j];
          Bs[bk * PAD + bn0 + j] = v;
        }
      }
    }
    __syncthreads();
#pragma unroll
    for (int kk = 0; kk < BK; ++kk) {
      float4 av = *(const float4*)(&As[kk * PAD + tm]);
      float4 bv = *(const float4*)(&Bs[kk * PAD + tn]);
      float a[4] = {av.x, av.y, av.z, av.w};
      float b[4] = {bv.x, bv.y, bv.z, bv.w};
#pragma unroll
      for (int i = 0; i < 4; ++i)
#pragma unroll
        for (int j = 0; j < 4; ++j)
          acc[i][j] += a[i] * b[j];
    }
    __syncthreads();
  }

#pragma unroll
  for (int i = 0; i < 4; ++i) {
    int row = brow + tm + i;
    if (row >= M) continue;
#pragma unroll
    for (int j = 0; j < 4; ++j) {
      int col = bcol + tn + j;
      if (col >= Nn) continue;
      float v = acc[i][j];
      if (bias) v += bias[col];
      C[(size_t)row * ldc + col] = v;
    }
  }
}

// ---------------- edge gather + atomic scatter for one relation ----------------
// one wave per edge iteration; lane covers 4 consecutive features (64*4 = 256)
__global__ __launch_bounds__(256) void edge_scatter(
    const int* __restrict__ src, const int* __restrict__ dst,
    const int* __restrict__ etype, int rel,
    const float* __restrict__ y, float* __restrict__ hnext)
{
  int gw = (blockIdx.x * 256 + threadIdx.x) >> 6;
  int lane = threadIdx.x & 63;
  int nw = (gridDim.x * 256) >> 6;
  for (int e = gw; e < NE; e += nw) {
    if (etype[e] != rel) continue;
    int s = src[e], d = dst[e];
    const float4 v = *(const float4*)(y + (size_t)s * HID + lane * 4);
    float* hp = hnext + (size_t)d * HID + lane * 4;
    unsafeAtomicAdd(hp + 0, v.x);
    unsafeAtomicAdd(hp + 1, v.y);
    unsafeAtomicAdd(hp + 2, v.z);
    unsafeAtomicAdd(hp + 3, v.w);
  }
}

__global__ __launch_bounds__(256) void relu_k(float* __restrict__ x, int n) {
  int i = blockIdx.x * 256 + threadIdx.x;
  int stride = gridDim.x * 256;
  for (; i < n; i += stride) x[i] = fmaxf(x[i], 0.f);
}

extern "C" void kernel_launch(void* const* d_in, const int* in_sizes, int n_in,
                              void* d_out, int out_size, void* d_ws, size_t ws_size,
                              hipStream_t stream) {
  const int*   srcp      = (const int*)d_in[0];
  const int*   dstp      = (const int*)d_in[1];
  const int*   etypep    = (const int*)d_in[2];
  const float* poi_dist  = (const float*)d_in[3];
  const float* time_dist = (const float*)d_in[4];
  const float* road_feat = (const float*)d_in[5];
  const float* poi_w     = (const float*)d_in[6];
  const float* poi_b     = (const float*)d_in[7];
  const float* time_w    = (const float*)d_in[8];
  const float* time_b    = (const float*)d_in[9];
  const float* road_w    = (const float*)d_in[10];
  const float* road_b    = (const float*)d_in[11];
  const float* basis1    = (const float*)d_in[12];
  const float* coef1     = (const float*)d_in[13];
  const float* loop_w1   = (const float*)d_in[14];
  const float* bias1     = (const float*)d_in[15];
  const float* basis2    = (const float*)d_in[16];
  const float* coef2     = (const float*)d_in[17];
  const float* loop_w2   = (const float*)d_in[18];
  const float* bias2     = (const float*)d_in[19];

  float* out = (float*)d_out;

  // ws layout (bytes):
  //   W1: 8*256*256*4 = 2,097,152
  //   W2: 2,097,152
  //   h1: 20000*256*4 = 20,480,000
  //   y : 20,480,000
  // total ~45.2 MB.  feat aliases d_out (dead before layer-2 writes out).
  char* ws = (char*)d_ws;
  float* W1   = (float*)(ws);
  float* W2   = (float*)(ws + 2097152);
  float* h1   = (float*)(ws + 2 * 2097152);
  float* y    = (float*)(ws + 2 * 2097152 + 20480000);
  float* feat = out;

  dim3 blk(256);

  // relation weight matrices
  make_W<<<(NR * HID * HID + 255) / 256, blk, 0, stream>>>(coef1, basis1, W1);
  make_W<<<(NR * HID * HID + 255) / 256, blk, 0, stream>>>(coef2, basis2, W2);

  const int MG = (NN + BM - 1) / BM;  // 313

  // input projections -> feat (N x 256), column blocks [0:64|64:192|192:256]
  sgemm<<<dim3(MG, 1), blk, 0, stream>>>(NN, 64, KPOI, poi_dist, KPOI,
                                         poi_w, 64, poi_b, feat + 0, HID);
  sgemm<<<dim3(MG, 2), blk, 0, stream>>>(NN, 128, KTIME, time_dist, KTIME,
                                         time_w, 128, time_b, feat + 64, HID);
  sgemm<<<dim3(MG, 1), blk, 0, stream>>>(NN, 64, KROAD, road_feat, KROAD,
                                         road_w, 64, road_b, feat + 192, HID);

  // ---- layer 1 ----
  sgemm<<<dim3(MG, 4), blk, 0, stream>>>(NN, HID, HID, feat, HID,
                                         loop_w1, HID, bias1, h1, HID);
  for (int r = 0; r < NR; ++r) {
    sgemm<<<dim3(MG, 4), blk, 0, stream>>>(NN, HID, HID, feat, HID,
                                           W1 + (size_t)r * HID * HID, HID,
                                           nullptr, y, HID);
    edge_scatter<<<1024, blk, 0, stream>>>(srcp, dstp, etypep, r, y, h1);
  }
  relu_k<<<2048, blk, 0, stream>>>(h1, NN * HID);

  // ---- layer 2 ----
  sgemm<<<dim3(MG, 4), blk, 0, stream>>>(NN, HID, HID, h1, HID,
                                         loop_w2, HID, bias2, out, HID);
  for (int r = 0; r < NR; ++r) {
    sgemm<<<dim3(MG, 4), blk, 0, stream>>>(NN, HID, HID, h1, HID,
                                           W2 + (size_t)r * HID * HID, HID,
                                           nullptr, y, HID);
    edge_scatter<<<1024, blk, 0, stream>>>(srcp, dstp, etypep, r, y, out);
  }
}

// Round 2
// 1699.794 us; speedup vs baseline: 3.3098x; 3.3098x over previous
//
#include <hip/hip_runtime.h>

#define NN 20000
#define NE 640000
#define NR 8
#define NB 8
#define HID 256
#define KPOI 12
#define KTIME 2880
#define KROAD 128
#define NK (NN * NR)   // 160000 (dst,rel) keys

// ---------------- W[r] = sum_b coef[r,b] * basis[b] ----------------
__global__ __launch_bounds__(256) void make_W(const float* __restrict__ coef,
                                              const float* __restrict__ basis,
                                              float* __restrict__ W) {
  int idx = blockIdx.x * 256 + threadIdx.x;
  if (idx >= NR * HID * HID) return;
  int r = idx / (HID * HID);
  int io = idx - r * (HID * HID);
  float acc = 0.f;
#pragma unroll
  for (int b = 0; b < NB; ++b)
    acc += coef[r * NB + b] * basis[b * HID * HID + io];
  W[idx] = acc;
}

// ---------------- tiled f32 GEMM: C = A@B (+bias), row-major ----------------
#define BK 16
template<int BM, int BN, int TM, int TN>
__global__ __launch_bounds__(256) void sgemm(
    int M, int Nn, int K,
    const float* __restrict__ A, int lda,
    const float* __restrict__ B, int ldb,
    const float* __restrict__ bias,
    float* __restrict__ C, int ldc)
{
  constexpr int SA = BM + 4;
  constexpr int SB = BN + 4;
  __shared__ float As[BK * SA];  // As[k][m]
  __shared__ float Bs[BK * SB];  // Bs[k][n]
  const int tid = threadIdx.x;
  const int brow = blockIdx.x * BM;
  const int bcol = blockIdx.y * BN;
  constexpr int TCOLS = BN / TN;   // (BM/TM)*(BN/TN) == 256
  const int row0 = (tid / TCOLS) * TM;
  const int col0 = (tid % TCOLS) * TN;

  float acc[TM][TN] = {};

  for (int kb = 0; kb < K; kb += BK) {
    // ---- A tile (BM x BK) -> As[k][m] transposed ----
    constexpr int AIT = (BM * 4) / 256;
#pragma unroll
    for (int it = 0; it < AIT; ++it) {
      int i = tid + it * 256;
      int r = i >> 2, q = (i & 3) * 4;
      int grow = brow + r, gk = kb + q;
      if (grow < M && gk + 3 < K) {
        float4 v = *(const float4*)(A + (size_t)grow * lda + gk);
        As[(q + 0) * SA + r] = v.x;
        As[(q + 1) * SA + r] = v.y;
        As[(q + 2) * SA + r] = v.z;
        As[(q + 3) * SA + r] = v.w;
      } else {
#pragma unroll
        for (int j = 0; j < 4; ++j)
          As[(q + j) * SA + r] =
              (grow < M && gk + j < K) ? A[(size_t)grow * lda + gk + j] : 0.f;
      }
    }
    // ---- B tile (BK x BN) -> Bs[k][n] ----
    constexpr int BIT = (BN * 4) / 256;
#pragma unroll
    for (int it = 0; it < BIT; ++it) {
      int i = tid + it * 256;
      int k = i / (BN / 4), cq = (i % (BN / 4)) * 4;
      int gk = kb + k, gc = bcol + cq;
      float4 v = {0.f, 0.f, 0.f, 0.f};
      if (gk < K) {
        if (gc + 3 < Nn) {
          v = *(const float4*)(B + (size_t)gk * ldb + gc);
        } else {
#pragma unroll
          for (int j = 0; j < 4; ++j)
            if (gc + j < Nn) (&v.x)[j] = B[(size_t)gk * ldb + gc + j];
        }
      }
      *(float4*)(&Bs[k * SB + cq]) = v;
    }
    __syncthreads();
#pragma unroll
    for (int kk = 0; kk < BK; ++kk) {
      float a[TM], b[TN];
#pragma unroll
      for (int i = 0; i < TM; i += 4)
        *(float4*)(&a[i]) = *(const float4*)(&As[kk * SA + row0 + i]);
#pragma unroll
      for (int j = 0; j < TN; j += 4)
        *(float4*)(&b[j]) = *(const float4*)(&Bs[kk * SB + col0 + j]);
#pragma unroll
      for (int i = 0; i < TM; ++i)
#pragma unroll
        for (int j = 0; j < TN; ++j)
          acc[i][j] += a[i] * b[j];
    }
    __syncthreads();
  }

  // ---- epilogue ----
  float bcache[TN];
#pragma unroll
  for (int j = 0; j < TN; ++j)
    bcache[j] = bias ? bias[bcol + col0 + j] : 0.f;
#pragma unroll
  for (int i = 0; i < TM; ++i) {
    int row = brow + row0 + i;
    if (row >= M) continue;
#pragma unroll
    for (int j = 0; j < TN; j += 4) {
      int col = bcol + col0 + j;
      if (col + 3 < Nn) {
        float4 v = {acc[i][j] + bcache[j], acc[i][j + 1] + bcache[j + 1],
                    acc[i][j + 2] + bcache[j + 2], acc[i][j + 3] + bcache[j + 3]};
        *(float4*)(C + (size_t)row * ldc + col) = v;
      } else {
#pragma unroll
        for (int jj = 0; jj < 4; ++jj)
          if (col + jj < Nn)
            C[(size_t)row * ldc + col + jj] = acc[i][j + jj] + bcache[j + jj];
      }
    }
  }
}

// ---------------- CSR build: key = dst*NR + etype ----------------
__global__ __launch_bounds__(256) void hist_k(const int* __restrict__ dst,
                                              const int* __restrict__ et,
                                              int* __restrict__ counts) {
  int e = blockIdx.x * 256 + threadIdx.x;
  if (e < NE) atomicAdd(&counts[dst[e] * NR + et[e]], 1);
}

// block scans 1024 elements (256 thr x 4); writes local-exclusive + block sum
__global__ __launch_bounds__(256) void scan_block(const int* __restrict__ counts,
                                                  int* __restrict__ offs,
                                                  int* __restrict__ bsums) {
  __shared__ int sh[256];
  int base = blockIdx.x * 1024;
  int t = threadIdx.x;
  int v[4];
  int s = 0;
#pragma unroll
  for (int j = 0; j < 4; ++j) {
    int idx = base + t * 4 + j;
    v[j] = (idx < NK) ? counts[idx] : 0;
    s += v[j];
  }
  sh[t] = s;
  __syncthreads();
  for (int off = 1; off < 256; off <<= 1) {
    int x = (t >= off) ? sh[t - off] : 0;
    __syncthreads();
    sh[t] += x;
    __syncthreads();
  }
  int run = sh[t] - s;  // exclusive prefix of this thread's chunk
#pragma unroll
  for (int j = 0; j < 4; ++j) {
    int idx = base + t * 4 + j;
    if (idx < NK) offs[idx] = run;
    run += v[j];
  }
  if (t == 255) bsums[blockIdx.x] = sh[255];
}

__global__ __launch_bounds__(256) void scan_bsums(int* __restrict__ bsums, int nblk) {
  __shared__ int sh[256];
  int t = threadIdx.x;
  int own = (t < nblk) ? bsums[t] : 0;
  sh[t] = own;
  __syncthreads();
  for (int off = 1; off < 256; off <<= 1) {
    int x = (t >= off) ? sh[t - off] : 0;
    __syncthreads();
    sh[t] += x;
    __syncthreads();
  }
  int ex = sh[t] - own;  // exclusive
  if (t < nblk) bsums[t] = ex;
}

__global__ __launch_bounds__(256) void add_base(int* __restrict__ offs,
                                                const int* __restrict__ bsums) {
  int idx = blockIdx.x * 256 + threadIdx.x;
  if (idx < NK) offs[idx] += bsums[idx >> 10];
  if (idx == NK) offs[NK] = NE;
}

__global__ __launch_bounds__(256) void copy_int(const int* __restrict__ a,
                                                int* __restrict__ b, int n) {
  int i = blockIdx.x * 256 + threadIdx.x;
  if (i < n) b[i] = a[i];
}

__global__ __launch_bounds__(256) void fill_k(const int* __restrict__ src,
                                              const int* __restrict__ dst,
                                              const int* __restrict__ et,
                                              int* __restrict__ cursor,
                                              unsigned short* __restrict__ ssrc) {
  int e = blockIdx.x * 256 + threadIdx.x;
  if (e < NE) {
    int key = dst[e] * NR + et[e];
    int p = atomicAdd(&cursor[key], 1);
    ssrc[p] = (unsigned short)src[e];
  }
}

// ---------------- segmented aggregation: h[d] += sum_{e in seg(d,rel)} y[src_e]
// one wave per dst node, lane covers 4 floats (64*4 = 256)
__global__ __launch_bounds__(256) void aggregate_k(
    const int* __restrict__ offs, const unsigned short* __restrict__ ssrc,
    int rel, const float* __restrict__ y, float* __restrict__ h) {
  int w = (blockIdx.x * 256 + threadIdx.x) >> 6;
  int lane = threadIdx.x & 63;
  if (w >= NN) return;
  int lo = offs[w * NR + rel];
  int hi = offs[w * NR + rel + 1];
  if (lo == hi) return;
  float4 acc = *(const float4*)(h + (size_t)w * HID + lane * 4);
  for (int e = lo; e < hi; ++e) {
    int s = ssrc[e];
    const float4 v = *(const float4*)(y + (size_t)s * HID + lane * 4);
    acc.x += v.x; acc.y += v.y; acc.z += v.z; acc.w += v.w;
  }
  *(float4*)(h + (size_t)w * HID + lane * 4) = acc;
}

__global__ __launch_bounds__(256) void relu_k(float* __restrict__ x, int n) {
  int i = blockIdx.x * 256 + threadIdx.x;
  int stride = gridDim.x * 256;
  for (; i < n; i += stride) x[i] = fmaxf(x[i], 0.f);
}

extern "C" void kernel_launch(void* const* d_in, const int* in_sizes, int n_in,
                              void* d_out, int out_size, void* d_ws, size_t ws_size,
                              hipStream_t stream) {
  const int*   srcp      = (const int*)d_in[0];
  const int*   dstp      = (const int*)d_in[1];
  const int*   etypep    = (const int*)d_in[2];
  const float* poi_dist  = (const float*)d_in[3];
  const float* time_dist = (const float*)d_in[4];
  const float* road_feat = (const float*)d_in[5];
  const float* poi_w     = (const float*)d_in[6];
  const float* poi_b     = (const float*)d_in[7];
  const float* time_w    = (const float*)d_in[8];
  const float* time_b    = (const float*)d_in[9];
  const float* road_w    = (const float*)d_in[10];
  const float* road_b    = (const float*)d_in[11];
  const float* basis1    = (const float*)d_in[12];
  const float* coef1     = (const float*)d_in[13];
  const float* loop_w1   = (const float*)d_in[14];
  const float* bias1     = (const float*)d_in[15];
  const float* basis2    = (const float*)d_in[16];
  const float* coef2     = (const float*)d_in[17];
  const float* loop_w2   = (const float*)d_in[18];
  const float* bias2     = (const float*)d_in[19];

  float* out = (float*)d_out;

  // ws layout (bytes), total 44,981,248 <= proven 45.15 MB budget:
  //   W        @ 0          (2,097,152)   one buffer, W1 then W2
  //   h1       @ 2,097,152  (20,480,000)
  //   y        @ 22,577,152 (20,480,000)
  //   offs     @ 43,057,152 ((NK+1)*4 = 640,004; pad)
  //   bsums    @ 43,697,168 (1,024)
  //   ssrc u16 @ 43,701,248 (1,280,000)
  // aliased (dead before first real use of host region):
  //   counts  -> y region   (640,000)
  //   cursor  -> h1 region  (640,000)
  char* ws = (char*)d_ws;
  float*          W      = (float*)(ws);
  float*          h1     = (float*)(ws + 2097152);
  float*          y      = (float*)(ws + 22577152);
  int*            offs   = (int*)  (ws + 43057152);
  int*            bsums  = (int*)  (ws + 43697168);
  unsigned short* ssrc   = (unsigned short*)(ws + 43701248);
  int*            counts = (int*)y;
  int*            cursor = (int*)h1;
  float*          feat   = out;

  dim3 blk(256);
  const int MG64  = (NN + 63) / 64;    // 313
  const int MG128 = (NN + 127) / 128;  // 157

  // ---- CSR build (once; reused by both layers) ----
  hipMemsetAsync(counts, 0, NK * sizeof(int), stream);
  hist_k<<<NE / 256, blk, 0, stream>>>(dstp, etypep, counts);
  scan_block<<<(NK + 1023) / 1024, blk, 0, stream>>>(counts, offs, bsums);
  scan_bsums<<<1, blk, 0, stream>>>(bsums, (NK + 1023) / 1024);
  add_base<<<(NK + 1 + 255) / 256, blk, 0, stream>>>(offs, bsums);
  copy_int<<<(NK + 255) / 256, blk, 0, stream>>>(offs, cursor, NK);
  fill_k<<<NE / 256, blk, 0, stream>>>(srcp, dstp, etypep, cursor, ssrc);

  // ---- input projections -> feat (N x 256) ----
  sgemm<64, 64, 4, 4><<<dim3(MG64, 1), blk, 0, stream>>>(
      NN, 64, KPOI, poi_dist, KPOI, poi_w, 64, poi_b, feat + 0, HID);
  sgemm<64, 64, 4, 4><<<dim3(MG64, 2), blk, 0, stream>>>(
      NN, 128, KTIME, time_dist, KTIME, time_w, 128, time_b, feat + 64, HID);
  sgemm<64, 64, 4, 4><<<dim3(MG64, 1), blk, 0, stream>>>(
      NN, 64, KROAD, road_feat, KROAD, road_w, 64, road_b, feat + 192, HID);

  // ---- layer 1 ----
  make_W<<<(NR * HID * HID + 255) / 256, blk, 0, stream>>>(coef1, basis1, W);
  sgemm<128, 128, 8, 8><<<dim3(MG128, 2), blk, 0, stream>>>(
      NN, HID, HID, feat, HID, loop_w1, HID, bias1, h1, HID);
  for (int r = 0; r < NR; ++r) {
    sgemm<128, 128, 8, 8><<<dim3(MG128, 2), blk, 0, stream>>>(
        NN, HID, HID, feat, HID, W + (size_t)r * HID * HID, HID, nullptr, y, HID);
    aggregate_k<<<(NN * 64 + 255) / 256, blk, 0, stream>>>(offs, ssrc, r, y, h1);
  }
  relu_k<<<2048, blk, 0, stream>>>(h1, NN * HID);

  // ---- layer 2 ----
  make_W<<<(NR * HID * HID + 255) / 256, blk, 0, stream>>>(coef2, basis2, W);
  sgemm<128, 128, 8, 8><<<dim3(MG128, 2), blk, 0, stream>>>(
      NN, HID, HID, h1, HID, loop_w2, HID, bias2, out, HID);
  for (int r = 0; r < NR; ++r) {
    sgemm<128, 128, 8, 8><<<dim3(MG128, 2), blk, 0, stream>>>(
        NN, HID, HID, h1, HID, W + (size_t)r * HID * HID, HID, nullptr, y, HID);
    aggregate_k<<<(NN * 64 + 255) / 256, blk, 0, stream>>>(offs, ssrc, r, y, out);
  }
}

// Round 3
// 1061.043 us; speedup vs baseline: 5.3022x; 1.6020x over previous
//
#include <hip/hip_runtime.h>

#define NN 20000
#define NE 640000
#define NR 8
#define NB 8
#define HID 256
#define KPOI 12
#define KTIME 2880
#define KROAD 128
#define NK (NN * NR)   // 160000 (dst,rel) keys

typedef __attribute__((ext_vector_type(8))) short bf8_t;   // 8 bf16 = 4 VGPR
typedef __attribute__((ext_vector_type(4))) float f4_t;

__device__ inline unsigned short f2bf(float f) {  // RNE f32->bf16
  unsigned int u = __float_as_uint(f);
  u += 0x7FFF + ((u >> 16) & 1);
  return (unsigned short)(u >> 16);
}

// ---------------- WT[r][o][i] = sum_b coef[r,b]*basis[b][i][o]  (bf16) ------
__global__ __launch_bounds__(256) void make_WT(const float* __restrict__ coef,
                                               const float* __restrict__ basis,
                                               unsigned short* __restrict__ WT) {
  int idx = blockIdx.x * 256 + threadIdx.x;   // r*65536 + o*256 + i
  if (idx >= NR * HID * HID) return;
  int r = idx >> 16;
  int o = (idx >> 8) & 255;
  int i = idx & 255;
  float acc = 0.f;
#pragma unroll
  for (int b = 0; b < NB; ++b)
    acc += coef[r * NB + b] * basis[b * HID * HID + i * HID + o];
  WT[idx] = f2bf(acc);
}

// ---------------- transpose + convert: out[c][r] = in[r][c] (bf16) ---------
__global__ __launch_bounds__(256) void transp_bf16(const float* __restrict__ in,
                                                   unsigned short* __restrict__ out,
                                                   int R, int Cc) {
  int idx = blockIdx.x * 256 + threadIdx.x;
  if (idx >= R * Cc) return;
  int r = idx / Cc, c = idx - r * Cc;
  out[(size_t)c * R + r] = f2bf(in[idx]);
}

// ---------------- MFMA GEMM: C(MxN,f32) = A(MxK,f32->bf16) @ BT(NxK,bf16)^T -
// requires K % 64 == 0; grid = (ceil(M/128), N/128); 256 threads = 4 waves 2x2
__global__ __launch_bounds__(256) void mfma_gemm(
    int M, int Nn, int K,
    const float* __restrict__ A, int lda,
    const unsigned short* __restrict__ BT,   // Nn x K row-major bf16
    const float* __restrict__ bias,
    float* __restrict__ C, int ldc)
{
  __shared__ __align__(16) char ldsA[128 * 128];  // 128 rows x (64 bf16 = 128B)
  __shared__ __align__(16) char ldsB[128 * 128];
  const int tid  = threadIdx.x;
  const int lane = tid & 63;
  const int w    = tid >> 6;
  const int wr   = w >> 1, wc = w & 1;
  const int brow = blockIdx.x * 128;
  const int bcol = blockIdx.y * 128;

  f4_t acc[4][4];
#pragma unroll
  for (int i = 0; i < 4; ++i)
#pragma unroll
    for (int j = 0; j < 4; ++j) acc[i][j] = (f4_t){0.f, 0.f, 0.f, 0.f};

  for (int kb = 0; kb < K; kb += 64) {
    // ---- stage A tile (128 x 64), f32 -> bf16, XOR-swizzled ----
#pragma unroll
    for (int it = 0; it < 4; ++it) {
      int slot = tid + it * 256;          // 1024 slots of 8 elems
      int r = slot >> 3, c8 = slot & 7;
      int grow = brow + r, gk = kb + c8 * 8;
      float v[8] = {0.f, 0.f, 0.f, 0.f, 0.f, 0.f, 0.f, 0.f};
      if (grow < M) {
        const float* ap = A + (size_t)grow * lda + gk;
        *(f4_t*)(v)     = *(const f4_t*)(ap);
        *(f4_t*)(v + 4) = *(const f4_t*)(ap + 4);
      }
      unsigned short hh[8];
#pragma unroll
      for (int j = 0; j < 8; ++j) hh[j] = f2bf(v[j]);
      *(bf8_t*)(ldsA + r * 128 + ((c8 * 16) ^ ((r & 7) << 4))) = *(bf8_t*)hh;
    }
    // ---- stage B tile (128 n-rows x 64 k), bf16 direct ----
#pragma unroll
    for (int it = 0; it < 4; ++it) {
      int slot = tid + it * 256;
      int r = slot >> 3, c8 = slot & 7;
      int gn = bcol + r, gk = kb + c8 * 8;
      bf8_t v = {0, 0, 0, 0, 0, 0, 0, 0};
      if (gn < Nn) v = *(const bf8_t*)(BT + (size_t)gn * K + gk);
      *(bf8_t*)(ldsB + r * 128 + ((c8 * 16) ^ ((r & 7) << 4))) = v;
    }
    __syncthreads();
    // ---- 2 x K=32 MFMA steps ----
#pragma unroll
    for (int ks = 0; ks < 2; ++ks) {
      const int kbyte = ks * 64 + (lane >> 4) * 16;
      bf8_t af[4], bfr[4];
#pragma unroll
      for (int mi = 0; mi < 4; ++mi) {
        int r = wr * 64 + mi * 16 + (lane & 15);
        af[mi] = *(const bf8_t*)(ldsA + r * 128 + (kbyte ^ ((r & 7) << 4)));
      }
#pragma unroll
      for (int ni = 0; ni < 4; ++ni) {
        int r = wc * 64 + ni * 16 + (lane & 15);
        bfr[ni] = *(const bf8_t*)(ldsB + r * 128 + (kbyte ^ ((r & 7) << 4)));
      }
#pragma unroll
      for (int mi = 0; mi < 4; ++mi)
#pragma unroll
        for (int ni = 0; ni < 4; ++ni)
          acc[mi][ni] = __builtin_amdgcn_mfma_f32_16x16x32_bf16(
              af[mi], bfr[ni], acc[mi][ni], 0, 0, 0);
    }
    __syncthreads();
  }

  // ---- epilogue: D col = lane&15, row = (lane>>4)*4 + j  [m89/m91] ----
  const int rq = (lane >> 4) * 4;
  const int cl = lane & 15;
#pragma unroll
  for (int ni = 0; ni < 4; ++ni) {
    int c = bcol + wc * 64 + ni * 16 + cl;
    float bv = bias ? bias[c] : 0.f;
#pragma unroll
    for (int mi = 0; mi < 4; ++mi) {
      int r0 = brow + wr * 64 + mi * 16 + rq;
#pragma unroll
      for (int j = 0; j < 4; ++j) {
        int r = r0 + j;
        if (r < M) C[(size_t)r * ldc + c] = acc[mi][ni][j] + bv;
      }
    }
  }
}

// ---------------- f32 tiled GEMM (kept for tiny poi/road projections) ------
#define BK 16
template<int BM, int BN, int TM, int TN>
__global__ __launch_bounds__(256) void sgemm(
    int M, int Nn, int K,
    const float* __restrict__ A, int lda,
    const float* __restrict__ B, int ldb,
    const float* __restrict__ bias,
    float* __restrict__ C, int ldc)
{
  constexpr int SA = BM + 4;
  constexpr int SB = BN + 4;
  __shared__ float As[BK * SA];
  __shared__ float Bs[BK * SB];
  const int tid = threadIdx.x;
  const int brow = blockIdx.x * BM;
  const int bcol = blockIdx.y * BN;
  constexpr int TCOLS = BN / TN;
  const int row0 = (tid / TCOLS) * TM;
  const int col0 = (tid % TCOLS) * TN;

  float acc[TM][TN] = {};

  for (int kb = 0; kb < K; kb += BK) {
    constexpr int AIT = (BM * 4) / 256;
#pragma unroll
    for (int it = 0; it < AIT; ++it) {
      int i = tid + it * 256;
      int r = i >> 2, q = (i & 3) * 4;
      int grow = brow + r, gk = kb + q;
      if (grow < M && gk + 3 < K) {
        float4 v = *(const float4*)(A + (size_t)grow * lda + gk);
        As[(q + 0) * SA + r] = v.x;
        As[(q + 1) * SA + r] = v.y;
        As[(q + 2) * SA + r] = v.z;
        As[(q + 3) * SA + r] = v.w;
      } else {
#pragma unroll
        for (int j = 0; j < 4; ++j)
          As[(q + j) * SA + r] =
              (grow < M && gk + j < K) ? A[(size_t)grow * lda + gk + j] : 0.f;
      }
    }
    constexpr int BIT = (BN * 4) / 256;
#pragma unroll
    for (int it = 0; it < BIT; ++it) {
      int i = tid + it * 256;
      int k = i / (BN / 4), cq = (i % (BN / 4)) * 4;
      int gk = kb + k, gc = bcol + cq;
      float4 v = {0.f, 0.f, 0.f, 0.f};
      if (gk < K) {
        if (gc + 3 < Nn) {
          v = *(const float4*)(B + (size_t)gk * ldb + gc);
        } else {
#pragma unroll
          for (int j = 0; j < 4; ++j)
            if (gc + j < Nn) (&v.x)[j] = B[(size_t)gk * ldb + gc + j];
        }
      }
      *(float4*)(&Bs[k * SB + cq]) = v;
    }
    __syncthreads();
#pragma unroll
    for (int kk = 0; kk < BK; ++kk) {
      float a[TM], b[TN];
#pragma unroll
      for (int i = 0; i < TM; i += 4)
        *(float4*)(&a[i]) = *(const float4*)(&As[kk * SA + row0 + i]);
#pragma unroll
      for (int j = 0; j < TN; j += 4)
        *(float4*)(&b[j]) = *(const float4*)(&Bs[kk * SB + col0 + j]);
#pragma unroll
      for (int i = 0; i < TM; ++i)
#pragma unroll
        for (int j = 0; j < TN; ++j)
          acc[i][j] += a[i] * b[j];
    }
    __syncthreads();
  }

  float bcache[TN];
#pragma unroll
  for (int j = 0; j < TN; ++j)
    bcache[j] = bias ? bias[bcol + col0 + j] : 0.f;
#pragma unroll
  for (int i = 0; i < TM; ++i) {
    int row = brow + row0 + i;
    if (row >= M) continue;
#pragma unroll
    for (int j = 0; j < TN; j += 4) {
      int col = bcol + col0 + j;
      if (col + 3 < Nn) {
        float4 v = {acc[i][j] + bcache[j], acc[i][j + 1] + bcache[j + 1],
                    acc[i][j + 2] + bcache[j + 2], acc[i][j + 3] + bcache[j + 3]};
        *(float4*)(C + (size_t)row * ldc + col) = v;
      } else {
#pragma unroll
        for (int jj = 0; jj < 4; ++jj)
          if (col + jj < Nn)
            C[(size_t)row * ldc + col + jj] = acc[i][j + jj] + bcache[j + jj];
      }
    }
  }
}

// ---------------- CSR build: key = dst*NR + etype ----------------
__global__ __launch_bounds__(256) void hist_k(const int* __restrict__ dst,
                                              const int* __restrict__ et,
                                              int* __restrict__ counts) {
  int e = blockIdx.x * 256 + threadIdx.x;
  if (e < NE) atomicAdd(&counts[dst[e] * NR + et[e]], 1);
}

__global__ __launch_bounds__(256) void scan_block(const int* __restrict__ counts,
                                                  int* __restrict__ offs,
                                                  int* __restrict__ bsums) {
  __shared__ int sh[256];
  int base = blockIdx.x * 1024;
  int t = threadIdx.x;
  int v[4];
  int s = 0;
#pragma unroll
  for (int j = 0; j < 4; ++j) {
    int idx = base + t * 4 + j;
    v[j] = (idx < NK) ? counts[idx] : 0;
    s += v[j];
  }
  sh[t] = s;
  __syncthreads();
  for (int off = 1; off < 256; off <<= 1) {
    int x = (t >= off) ? sh[t - off] : 0;
    __syncthreads();
    sh[t] += x;
    __syncthreads();
  }
  int run = sh[t] - s;
#pragma unroll
  for (int j = 0; j < 4; ++j) {
    int idx = base + t * 4 + j;
    if (idx < NK) offs[idx] = run;
    run += v[j];
  }
  if (t == 255) bsums[blockIdx.x] = sh[255];
}

__global__ __launch_bounds__(256) void scan_bsums(int* __restrict__ bsums, int nblk) {
  __shared__ int sh[256];
  int t = threadIdx.x;
  int own = (t < nblk) ? bsums[t] : 0;
  sh[t] = own;
  __syncthreads();
  for (int off = 1; off < 256; off <<= 1) {
    int x = (t >= off) ? sh[t - off] : 0;
    __syncthreads();
    sh[t] += x;
    __syncthreads();
  }
  int ex = sh[t] - own;
  if (t < nblk) bsums[t] = ex;
}

__global__ __launch_bounds__(256) void add_base(int* __restrict__ offs,
                                                const int* __restrict__ bsums) {
  int idx = blockIdx.x * 256 + threadIdx.x;
  if (idx < NK) offs[idx] += bsums[idx >> 10];
  if (idx == NK) offs[NK] = NE;
}

__global__ __launch_bounds__(256) void copy_int(const int* __restrict__ a,
                                                int* __restrict__ b, int n) {
  int i = blockIdx.x * 256 + threadIdx.x;
  if (i < n) b[i] = a[i];
}

__global__ __launch_bounds__(256) void fill_k(const int* __restrict__ src,
                                              const int* __restrict__ dst,
                                              const int* __restrict__ et,
                                              int* __restrict__ cursor,
                                              unsigned short* __restrict__ ssrc) {
  int e = blockIdx.x * 256 + threadIdx.x;
  if (e < NE) {
    int key = dst[e] * NR + et[e];
    int p = atomicAdd(&cursor[key], 1);
    ssrc[p] = (unsigned short)src[e];
  }
}

// ---------------- segmented aggregation: one wave per dst node -------------
__global__ __launch_bounds__(256) void aggregate_k(
    const int* __restrict__ offs, const unsigned short* __restrict__ ssrc,
    int rel, const float* __restrict__ y, float* __restrict__ h) {
  int w = (blockIdx.x * 256 + threadIdx.x) >> 6;
  int lane = threadIdx.x & 63;
  if (w >= NN) return;
  int lo = offs[w * NR + rel];
  int hi = offs[w * NR + rel + 1];
  if (lo == hi) return;
  float4 acc = *(const float4*)(h + (size_t)w * HID + lane * 4);
  for (int e = lo; e < hi; ++e) {
    int s = ssrc[e];
    const float4 v = *(const float4*)(y + (size_t)s * HID + lane * 4);
    acc.x += v.x; acc.y += v.y; acc.z += v.z; acc.w += v.w;
  }
  *(float4*)(h + (size_t)w * HID + lane * 4) = acc;
}

__global__ __launch_bounds__(256) void relu_k(float* __restrict__ x, int n) {
  int i = blockIdx.x * 256 + threadIdx.x;
  int stride = gridDim.x * 256;
  for (; i < n; i += stride) x[i] = fmaxf(x[i], 0.f);
}

extern "C" void kernel_launch(void* const* d_in, const int* in_sizes, int n_in,
                              void* d_out, int out_size, void* d_ws, size_t ws_size,
                              hipStream_t stream) {
  const int*   srcp      = (const int*)d_in[0];
  const int*   dstp      = (const int*)d_in[1];
  const int*   etypep    = (const int*)d_in[2];
  const float* poi_dist  = (const float*)d_in[3];
  const float* time_dist = (const float*)d_in[4];
  const float* road_feat = (const float*)d_in[5];
  const float* poi_w     = (const float*)d_in[6];
  const float* poi_b     = (const float*)d_in[7];
  const float* time_w    = (const float*)d_in[8];
  const float* time_b    = (const float*)d_in[9];
  const float* road_w    = (const float*)d_in[10];
  const float* road_b    = (const float*)d_in[11];
  const float* basis1    = (const float*)d_in[12];
  const float* coef1     = (const float*)d_in[13];
  const float* loop_w1   = (const float*)d_in[14];
  const float* bias1     = (const float*)d_in[15];
  const float* basis2    = (const float*)d_in[16];
  const float* coef2     = (const float*)d_in[17];
  const float* loop_w2   = (const float*)d_in[18];
  const float* bias2     = (const float*)d_in[19];

  float* out = (float*)d_out;

  // ws layout (bytes), total 44,929,040 <= proven 45 MB budget:
  //   WT   bf16 @ 0          (1,048,576)  relation weights^T (reused L1->L2)
  //   LWT1 bf16 @ 1,048,576  (131,072)
  //   LWT2 bf16 @ 1,179,648  (131,072)
  //   TWT  bf16 @ 1,310,720  (737,280)    time_w^T
  //   h1   f32  @ 2,048,000  (20,480,000)
  //   y    f32  @ 22,528,000 (20,480,000)
  //   offs      @ 43,008,000 (640,016)
  //   bsums     @ 43,648,016 (1,024)
  //   ssrc u16  @ 43,649,040 (1,280,000)
  // aliases (dead before host region's first real use):
  //   counts -> y region, cursor -> h1 region
  char* ws = (char*)d_ws;
  unsigned short* WT     = (unsigned short*)(ws);
  unsigned short* LWT1   = (unsigned short*)(ws + 1048576);
  unsigned short* LWT2   = (unsigned short*)(ws + 1179648);
  unsigned short* TWT    = (unsigned short*)(ws + 1310720);
  float*          h1     = (float*)(ws + 2048000);
  float*          y      = (float*)(ws + 22528000);
  int*            offs   = (int*)  (ws + 43008000);
  int*            bsums  = (int*)  (ws + 43648016);
  unsigned short* ssrc   = (unsigned short*)(ws + 43649040);
  int*            counts = (int*)y;
  int*            cursor = (int*)h1;
  float*          feat   = out;

  dim3 blk(256);
  const int MG64  = (NN + 63) / 64;     // 313
  const int MGM   = (NN + 127) / 128;   // 157

  // ---- CSR build (uses counts->y, cursor->h1 aliases; done before GEMMs) ----
  hipMemsetAsync(counts, 0, NK * sizeof(int), stream);
  hist_k<<<NE / 256, blk, 0, stream>>>(dstp, etypep, counts);
  scan_block<<<(NK + 1023) / 1024, blk, 0, stream>>>(counts, offs, bsums);
  scan_bsums<<<1, blk, 0, stream>>>(bsums, (NK + 1023) / 1024);
  add_base<<<(NK + 1 + 255) / 256, blk, 0, stream>>>(offs, bsums);
  copy_int<<<(NK + 255) / 256, blk, 0, stream>>>(offs, cursor, NK);
  fill_k<<<NE / 256, blk, 0, stream>>>(srcp, dstp, etypep, cursor, ssrc);

  // ---- weight preprocessing (transpose + bf16) ----
  transp_bf16<<<(HID * HID + 255) / 256, blk, 0, stream>>>(loop_w1, LWT1, HID, HID);
  transp_bf16<<<(HID * HID + 255) / 256, blk, 0, stream>>>(loop_w2, LWT2, HID, HID);
  transp_bf16<<<(KTIME * 128 + 255) / 256, blk, 0, stream>>>(time_w, TWT, KTIME, 128);

  // ---- input projections -> feat (N x 256) ----
  sgemm<64, 64, 4, 4><<<dim3(MG64, 1), blk, 0, stream>>>(
      NN, 64, KPOI, poi_dist, KPOI, poi_w, 64, poi_b, feat + 0, HID);
  mfma_gemm<<<dim3(MGM, 1), blk, 0, stream>>>(
      NN, 128, KTIME, time_dist, KTIME, TWT, time_b, feat + 64, HID);
  sgemm<64, 64, 4, 4><<<dim3(MG64, 1), blk, 0, stream>>>(
      NN, 64, KROAD, road_feat, KROAD, road_w, 64, road_b, feat + 192, HID);

  // ---- layer 1 ----
  make_WT<<<(NR * HID * HID + 255) / 256, blk, 0, stream>>>(coef1, basis1, WT);
  mfma_gemm<<<dim3(MGM, 2), blk, 0, stream>>>(
      NN, HID, HID, feat, HID, LWT1, bias1, h1, HID);
  for (int r = 0; r < NR; ++r) {
    mfma_gemm<<<dim3(MGM, 2), blk, 0, stream>>>(
        NN, HID, HID, feat, HID, WT + (size_t)r * HID * HID, nullptr, y, HID);
    aggregate_k<<<(NN * 64 + 255) / 256, blk, 0, stream>>>(offs, ssrc, r, y, h1);
  }
  relu_k<<<2048, blk, 0, stream>>>(h1, NN * HID);

  // ---- layer 2 ----
  make_WT<<<(NR * HID * HID + 255) / 256, blk, 0, stream>>>(coef2, basis2, WT);
  mfma_gemm<<<dim3(MGM, 2), blk, 0, stream>>>(
      NN, HID, HID, h1, HID, LWT2, bias2, out, HID);
  for (int r = 0; r < NR; ++r) {
    mfma_gemm<<<dim3(MGM, 2), blk, 0, stream>>>(
        NN, HID, HID, h1, HID, WT + (size_t)r * HID * HID, nullptr, y, HID);
    aggregate_k<<<(NN * 64 + 255) / 256, blk, 0, stream>>>(offs, ssrc, r, y, out);
  }
}

// Round 4
// 586.255 us; speedup vs baseline: 9.5963x; 1.8099x over previous
//
#include <hip/hip_runtime.h>

#define NN 20000
#define NE 640000
#define NR 8
#define NB 8
#define HID 256
#define KPOI 12
#define KTIME 2880
#define KROAD 128
#define NK (NN * NR)   // 160000 (dst,rel) keys

typedef __attribute__((ext_vector_type(8))) short bf8_t;   // 8 bf16 = 4 VGPR
typedef __attribute__((ext_vector_type(4))) float f4_t;

__device__ inline unsigned short f2bf(float f) {  // RNE f32->bf16
  unsigned int u = __float_as_uint(f);
  u += 0x7FFF + ((u >> 16) & 1);
  return (unsigned short)(u >> 16);
}
__device__ inline float bf2f(unsigned short h) {
  return __uint_as_float((unsigned int)h << 16);
}

// ---------------- WT[r][o][i] = sum_b coef[r,b]*basis[b][i][o]  (bf16) ------
__global__ __launch_bounds__(256) void make_WT(const float* __restrict__ coef,
                                               const float* __restrict__ basis,
                                               unsigned short* __restrict__ WT) {
  int idx = blockIdx.x * 256 + threadIdx.x;   // r*65536 + o*256 + i
  if (idx >= NR * HID * HID) return;
  int r = idx >> 16;
  int o = (idx >> 8) & 255;
  int i = idx & 255;
  float acc = 0.f;
#pragma unroll
  for (int b = 0; b < NB; ++b)
    acc += coef[r * NB + b] * basis[b * HID * HID + i * HID + o];
  WT[idx] = f2bf(acc);
}

// ---------------- transpose + convert: out[c][r] = in[r][c] (bf16) ---------
__global__ __launch_bounds__(256) void transp_bf16(const float* __restrict__ in,
                                                   unsigned short* __restrict__ out,
                                                   int R, int Cc) {
  int idx = blockIdx.x * 256 + threadIdx.x;
  if (idx >= R * Cc) return;
  int r = idx / Cc, c = idx - r * Cc;
  out[(size_t)c * R + r] = f2bf(in[idx]);
}

// ---------------- small f32 GEMM -> bf16 out (poi / road projections) ------
#define BK 16
template<int BM, int BN, int TM, int TN>
__global__ __launch_bounds__(256) void sgemm_bf(
    int M, int Nn, int K,
    const float* __restrict__ A, int lda,
    const float* __restrict__ B, int ldb,
    const float* __restrict__ bias,
    unsigned short* __restrict__ C, int ldc)
{
  constexpr int SA = BM + 4;
  constexpr int SB = BN + 4;
  __shared__ float As[BK * SA];
  __shared__ float Bs[BK * SB];
  const int tid = threadIdx.x;
  const int brow = blockIdx.x * BM;
  const int bcol = blockIdx.y * BN;
  constexpr int TCOLS = BN / TN;
  const int row0 = (tid / TCOLS) * TM;
  const int col0 = (tid % TCOLS) * TN;

  float acc[TM][TN] = {};

  for (int kb = 0; kb < K; kb += BK) {
    constexpr int AIT = (BM * 4) / 256;
#pragma unroll
    for (int it = 0; it < AIT; ++it) {
      int i = tid + it * 256;
      int r = i >> 2, q = (i & 3) * 4;
      int grow = brow + r, gk = kb + q;
      if (grow < M && gk + 3 < K) {
        float4 v = *(const float4*)(A + (size_t)grow * lda + gk);
        As[(q + 0) * SA + r] = v.x;
        As[(q + 1) * SA + r] = v.y;
        As[(q + 2) * SA + r] = v.z;
        As[(q + 3) * SA + r] = v.w;
      } else {
#pragma unroll
        for (int j = 0; j < 4; ++j)
          As[(q + j) * SA + r] =
              (grow < M && gk + j < K) ? A[(size_t)grow * lda + gk + j] : 0.f;
      }
    }
    constexpr int BIT = (BN * 4) / 256;
#pragma unroll
    for (int it = 0; it < BIT; ++it) {
      int i = tid + it * 256;
      int k = i / (BN / 4), cq = (i % (BN / 4)) * 4;
      int gk = kb + k, gc = bcol + cq;
      float4 v = {0.f, 0.f, 0.f, 0.f};
      if (gk < K) {
        if (gc + 3 < Nn) {
          v = *(const float4*)(B + (size_t)gk * ldb + gc);
        } else {
#pragma unroll
          for (int j = 0; j < 4; ++j)
            if (gc + j < Nn) (&v.x)[j] = B[(size_t)gk * ldb + gc + j];
        }
      }
      *(float4*)(&Bs[k * SB + cq]) = v;
    }
    __syncthreads();
#pragma unroll
    for (int kk = 0; kk < BK; ++kk) {
      float a[TM], b[TN];
#pragma unroll
      for (int i = 0; i < TM; i += 4)
        *(float4*)(&a[i]) = *(const float4*)(&As[kk * SA + row0 + i]);
#pragma unroll
      for (int j = 0; j < TN; j += 4)
        *(float4*)(&b[j]) = *(const float4*)(&Bs[kk * SB + col0 + j]);
#pragma unroll
      for (int i = 0; i < TM; ++i)
#pragma unroll
        for (int j = 0; j < TN; ++j)
          acc[i][j] += a[i] * b[j];
    }
    __syncthreads();
  }

  float bcache[TN];
#pragma unroll
  for (int j = 0; j < TN; ++j)
    bcache[j] = bias ? bias[bcol + col0 + j] : 0.f;
#pragma unroll
  for (int i = 0; i < TM; ++i) {
    int row = brow + row0 + i;
    if (row >= M) continue;
#pragma unroll
    for (int j = 0; j < TN; ++j) {
      int col = bcol + col0 + j;
      if (col < Nn)
        C[(size_t)row * ldc + col] = f2bf(acc[i][j] + bcache[j]);
    }
  }
}

// ---------------- time GEMM: featb[:,64:192] = time_dist @ TWT^T + b -------
// tile 32 rows x 128 cols, 625 blocks (20000/32 exact), 4 waves, K=2880
__global__ __launch_bounds__(256) void mfma_time(
    const float* __restrict__ A,            // [NN][2880] f32
    const unsigned short* __restrict__ BT,  // [128][2880] bf16
    const float* __restrict__ bias,         // [128]
    unsigned short* __restrict__ featb)     // [NN][256]
{
  __shared__ __align__(16) char ldsA[32 * 128];
  __shared__ __align__(16) char ldsB[128 * 128];
  const int tid = threadIdx.x;
  const int lane = tid & 63;
  const int w = tid >> 6;            // 0..3 -> col block w*32
  const int brow = blockIdx.x * 32;

  f4_t acc[2][2];
#pragma unroll
  for (int i = 0; i < 2; ++i)
#pragma unroll
    for (int j = 0; j < 2; ++j) acc[i][j] = (f4_t){0.f, 0.f, 0.f, 0.f};

  for (int kb = 0; kb < KTIME; kb += 64) {
    {  // A: 32 rows x 64 k, f32 -> bf16 (256 slots of 8 elems)
      int r = tid >> 3, c8 = tid & 7;
      const float* ap = A + (size_t)(brow + r) * KTIME + kb + c8 * 8;
      f4_t v0 = *(const f4_t*)ap;
      f4_t v1 = *(const f4_t*)(ap + 4);
      unsigned short hh[8];
#pragma unroll
      for (int j = 0; j < 4; ++j) { hh[j] = f2bf(v0[j]); hh[4 + j] = f2bf(v1[j]); }
      *(bf8_t*)(ldsA + r * 128 + ((c8 * 16) ^ ((r & 7) << 4))) = *(bf8_t*)hh;
    }
#pragma unroll
    for (int it = 0; it < 4; ++it) {  // B: 128 rows x 64 k
      int slot = tid + it * 256;
      int r = slot >> 3, c8 = slot & 7;
      bf8_t v = *(const bf8_t*)(BT + (size_t)r * KTIME + kb + c8 * 8);
      *(bf8_t*)(ldsB + r * 128 + ((c8 * 16) ^ ((r & 7) << 4))) = v;
    }
    __syncthreads();
#pragma unroll
    for (int ks = 0; ks < 2; ++ks) {
      const int kbyte = ks * 64 + (lane >> 4) * 16;
      bf8_t af[2], bfr[2];
#pragma unroll
      for (int mi = 0; mi < 2; ++mi) {
        int m = mi * 16 + (lane & 15);
        af[mi] = *(const bf8_t*)(ldsA + m * 128 + (kbyte ^ ((m & 7) << 4)));
      }
#pragma unroll
      for (int ni = 0; ni < 2; ++ni) {
        int n = w * 32 + ni * 16 + (lane & 15);
        bfr[ni] = *(const bf8_t*)(ldsB + n * 128 + (kbyte ^ ((n & 7) << 4)));
      }
#pragma unroll
      for (int mi = 0; mi < 2; ++mi)
#pragma unroll
        for (int ni = 0; ni < 2; ++ni)
          acc[mi][ni] = __builtin_amdgcn_mfma_f32_16x16x32_bf16(
              af[mi], bfr[ni], acc[mi][ni], 0, 0, 0);
    }
    __syncthreads();
  }

  const int rq = (lane >> 4) * 4;
  const int cl = lane & 15;
#pragma unroll
  for (int ni = 0; ni < 2; ++ni) {
    int c = w * 32 + ni * 16 + cl;
    float bv = bias[c];
#pragma unroll
    for (int mi = 0; mi < 2; ++mi) {
#pragma unroll
      for (int j = 0; j < 4; ++j) {
        int row = brow + mi * 16 + rq + j;   // always < 20000
        featb[(size_t)row * 256 + 64 + c] = f2bf(acc[mi][ni][j] + bv);
      }
    }
  }
}

// ---------------- fused RelGraphConv layer ----------------------------------
// block = 64 dst rows, 8 waves (512 thr). Per relation r (r=NR is self-loop):
//   aggregate Z[64][256] = sum of hin[src] rows (CSR) -> LDS bf16 (swizzled)
//   MFMA: acc += Z @ W_r   (W_r streamed in 4 K-chunks of 64)
// epilogue: +bias, optional relu, write bf16 and/or f32.
template<int RELU>
__global__ __launch_bounds__(512) void fused_layer(
    const int* __restrict__ offs,
    const unsigned short* __restrict__ ssrc,
    const unsigned short* __restrict__ hin,   // [NN][256] bf16
    const unsigned short* __restrict__ WT,    // [NR][256][256] bf16 (o-major)
    const unsigned short* __restrict__ LWT,   // [256][256] bf16 loop_w^T
    const float* __restrict__ bias,
    unsigned short* __restrict__ hout_bf,     // nullable
    float* __restrict__ hout_f32)             // nullable
{
  __shared__ __align__(16) char Zt[64 * 512];    // 32 KB
  __shared__ __align__(16) char Bt[256 * 128];   // 32 KB
  const int tid = threadIdx.x;
  const int lane = tid & 63;
  const int w = tid >> 6;        // 0..7
  const int wr = w >> 1;         // 0..3: rows wr*16..wr*16+15
  const int wc = w & 1;          // 0..1: cols wc*128..wc*128+127
  const int brow = blockIdx.x * 64;

  f4_t acc[8];
#pragma unroll
  for (int i = 0; i < 8; ++i) acc[i] = (f4_t){0.f, 0.f, 0.f, 0.f};

  for (int r = 0; r <= NR; ++r) {
    // ---- aggregate Z rows: wave w owns d_loc = w*8 .. w*8+7 ----
#pragma unroll 1
    for (int i = 0; i < 8; ++i) {
      int d_loc = w * 8 + i;
      int d = brow + d_loc;
      f4_t az = {0.f, 0.f, 0.f, 0.f};
      if (d < NN) {
        if (r < NR) {
          int lo = offs[d * NR + r];
          int hi = offs[d * NR + r + 1];
          int e = lo;
          for (; e + 4 <= hi; e += 4) {   // 4 gathers in flight
            int s0 = ssrc[e], s1 = ssrc[e + 1], s2 = ssrc[e + 2], s3 = ssrc[e + 3];
            ushort4 u0 = *(const ushort4*)(hin + (size_t)s0 * HID + lane * 4);
            ushort4 u1 = *(const ushort4*)(hin + (size_t)s1 * HID + lane * 4);
            ushort4 u2 = *(const ushort4*)(hin + (size_t)s2 * HID + lane * 4);
            ushort4 u3 = *(const ushort4*)(hin + (size_t)s3 * HID + lane * 4);
            az.x += (bf2f(u0.x) + bf2f(u1.x)) + (bf2f(u2.x) + bf2f(u3.x));
            az.y += (bf2f(u0.y) + bf2f(u1.y)) + (bf2f(u2.y) + bf2f(u3.y));
            az.z += (bf2f(u0.z) + bf2f(u1.z)) + (bf2f(u2.z) + bf2f(u3.z));
            az.w += (bf2f(u0.w) + bf2f(u1.w)) + (bf2f(u2.w) + bf2f(u3.w));
          }
          for (; e < hi; ++e) {
            int s = ssrc[e];
            ushort4 u = *(const ushort4*)(hin + (size_t)s * HID + lane * 4);
            az.x += bf2f(u.x); az.y += bf2f(u.y);
            az.z += bf2f(u.z); az.w += bf2f(u.w);
          }
        } else {  // self-loop: Z = hin[d]
          ushort4 u = *(const ushort4*)(hin + (size_t)d * HID + lane * 4);
          az = (f4_t){bf2f(u.x), bf2f(u.y), bf2f(u.z), bf2f(u.w)};
        }
      }
      unsigned short hz[4] = {f2bf(az.x), f2bf(az.y), f2bf(az.z), f2bf(az.w)};
      *(ushort4*)(Zt + d_loc * 512 + ((lane * 8) ^ ((d_loc & 7) << 4))) =
          *(ushort4*)hz;
    }
    __syncthreads();

    const unsigned short* Wsrc = (r < NR) ? (WT + (size_t)r * HID * HID) : LWT;
#pragma unroll 1
    for (int kc = 0; kc < 4; ++kc) {
#pragma unroll
      for (int it = 0; it < 4; ++it) {  // stage W chunk: 256 n-rows x 64 k
        int slot = tid + it * 512;      // 2048 slots of 8 elems
        int n = slot >> 3, c8 = slot & 7;
        bf8_t v = *(const bf8_t*)(Wsrc + (size_t)n * HID + kc * 64 + c8 * 8);
        *(bf8_t*)(Bt + n * 128 + ((c8 * 16) ^ ((n & 7) << 4))) = v;
      }
      __syncthreads();
#pragma unroll
      for (int ks = 0; ks < 2; ++ks) {
        const int kbyte = ks * 64 + (lane >> 4) * 16;
        int m = wr * 16 + (lane & 15);
        bf8_t af = *(const bf8_t*)(
            Zt + m * 512 + ((kc * 128 + kbyte) ^ ((m & 7) << 4)));
#pragma unroll
        for (int ni = 0; ni < 8; ++ni) {
          int n = wc * 128 + ni * 16 + (lane & 15);
          bf8_t bfr = *(const bf8_t*)(Bt + n * 128 + (kbyte ^ ((n & 7) << 4)));
          acc[ni] = __builtin_amdgcn_mfma_f32_16x16x32_bf16(af, bfr, acc[ni], 0, 0, 0);
        }
      }
      __syncthreads();
    }
  }

  // ---- epilogue: D col = lane&15, row = (lane>>4)*4 + j ----
  const int rq = (lane >> 4) * 4;
  const int cl = lane & 15;
#pragma unroll
  for (int ni = 0; ni < 8; ++ni) {
    int c = wc * 128 + ni * 16 + cl;
    float bv = bias[c];
#pragma unroll
    for (int j = 0; j < 4; ++j) {
      int row = brow + wr * 16 + rq + j;
      if (row < NN) {
        float v = acc[ni][j] + bv;
        if (RELU) v = fmaxf(v, 0.f);
        if (hout_bf)  hout_bf[(size_t)row * 256 + c] = f2bf(v);
        if (hout_f32) hout_f32[(size_t)row * 256 + c] = v;
      }
    }
  }
}

// ---------------- CSR build: key = dst*NR + etype ----------------
__global__ __launch_bounds__(256) void hist_k(const int* __restrict__ dst,
                                              const int* __restrict__ et,
                                              int* __restrict__ counts) {
  int e = blockIdx.x * 256 + threadIdx.x;
  if (e < NE) atomicAdd(&counts[dst[e] * NR + et[e]], 1);
}

__global__ __launch_bounds__(256) void scan_block(const int* __restrict__ counts,
                                                  int* __restrict__ offs,
                                                  int* __restrict__ bsums) {
  __shared__ int sh[256];
  int base = blockIdx.x * 1024;
  int t = threadIdx.x;
  int v[4];
  int s = 0;
#pragma unroll
  for (int j = 0; j < 4; ++j) {
    int idx = base + t * 4 + j;
    v[j] = (idx < NK) ? counts[idx] : 0;
    s += v[j];
  }
  sh[t] = s;
  __syncthreads();
  for (int off = 1; off < 256; off <<= 1) {
    int x = (t >= off) ? sh[t - off] : 0;
    __syncthreads();
    sh[t] += x;
    __syncthreads();
  }
  int run = sh[t] - s;
#pragma unroll
  for (int j = 0; j < 4; ++j) {
    int idx = base + t * 4 + j;
    if (idx < NK) offs[idx] = run;
    run += v[j];
  }
  if (t == 255) bsums[blockIdx.x] = sh[255];
}

__global__ __launch_bounds__(256) void scan_bsums(int* __restrict__ bsums, int nblk) {
  __shared__ int sh[256];
  int t = threadIdx.x;
  int own = (t < nblk) ? bsums[t] : 0;
  sh[t] = own;
  __syncthreads();
  for (int off = 1; off < 256; off <<= 1) {
    int x = (t >= off) ? sh[t - off] : 0;
    __syncthreads();
    sh[t] += x;
    __syncthreads();
  }
  int ex = sh[t] - own;
  if (t < nblk) bsums[t] = ex;
}

__global__ __launch_bounds__(256) void add_base(int* __restrict__ offs,
                                                const int* __restrict__ bsums) {
  int idx = blockIdx.x * 256 + threadIdx.x;
  if (idx < NK) offs[idx] += bsums[idx >> 10];
  if (idx == NK) offs[NK] = NE;
}

__global__ __launch_bounds__(256) void copy_int(const int* __restrict__ a,
                                                int* __restrict__ b, int n) {
  int i = blockIdx.x * 256 + threadIdx.x;
  if (i < n) b[i] = a[i];
}

__global__ __launch_bounds__(256) void fill_k(const int* __restrict__ src,
                                              const int* __restrict__ dst,
                                              const int* __restrict__ et,
                                              int* __restrict__ cursor,
                                              unsigned short* __restrict__ ssrc) {
  int e = blockIdx.x * 256 + threadIdx.x;
  if (e < NE) {
    int key = dst[e] * NR + et[e];
    int p = atomicAdd(&cursor[key], 1);
    ssrc[p] = (unsigned short)src[e];
  }
}

extern "C" void kernel_launch(void* const* d_in, const int* in_sizes, int n_in,
                              void* d_out, int out_size, void* d_ws, size_t ws_size,
                              hipStream_t stream) {
  const int*   srcp      = (const int*)d_in[0];
  const int*   dstp      = (const int*)d_in[1];
  const int*   etypep    = (const int*)d_in[2];
  const float* poi_dist  = (const float*)d_in[3];
  const float* time_dist = (const float*)d_in[4];
  const float* road_feat = (const float*)d_in[5];
  const float* poi_w     = (const float*)d_in[6];
  const float* poi_b     = (const float*)d_in[7];
  const float* time_w    = (const float*)d_in[8];
  const float* time_b    = (const float*)d_in[9];
  const float* road_w    = (const float*)d_in[10];
  const float* road_b    = (const float*)d_in[11];
  const float* basis1    = (const float*)d_in[12];
  const float* coef1     = (const float*)d_in[13];
  const float* loop_w1   = (const float*)d_in[14];
  const float* bias1     = (const float*)d_in[15];
  const float* basis2    = (const float*)d_in[16];
  const float* coef2     = (const float*)d_in[17];
  const float* loop_w2   = (const float*)d_in[18];
  const float* bias2     = (const float*)d_in[19];

  float* out = (float*)d_out;

  // ws layout (bytes), total 24,449,040:
  //   WT    bf16 @ 0          (1,048,576)   relation W^T, reused L1->L2
  //   LWT1  bf16 @ 1,048,576  (131,072)
  //   LWT2  bf16 @ 1,179,648  (131,072)
  //   TWT   bf16 @ 1,310,720  (737,280)     time_w^T
  //   featb bf16 @ 2,048,000  (10,240,000)  input features  (N x 256)
  //   h1b   bf16 @ 12,288,000 (10,240,000)  layer-1 output  (N x 256)
  //   offs       @ 22,528,000 (640,016)
  //   bsums      @ 23,168,016 (1,024)
  //   ssrc  u16  @ 23,169,040 (1,280,000)
  // aliases (dead before host region's first write):
  //   counts -> featb region, cursor -> h1b region
  char* ws = (char*)d_ws;
  unsigned short* WT     = (unsigned short*)(ws);
  unsigned short* LWT1   = (unsigned short*)(ws + 1048576);
  unsigned short* LWT2   = (unsigned short*)(ws + 1179648);
  unsigned short* TWT    = (unsigned short*)(ws + 1310720);
  unsigned short* featb  = (unsigned short*)(ws + 2048000);
  unsigned short* h1b    = (unsigned short*)(ws + 12288000);
  int*            offs   = (int*)  (ws + 22528000);
  int*            bsums  = (int*)  (ws + 23168016);
  unsigned short* ssrc   = (unsigned short*)(ws + 23169040);
  int*            counts = (int*)featb;
  int*            cursor = (int*)h1b;

  dim3 blk(256);

  // ---- CSR build (aliases are dead before featb/h1b first writes) ----
  hipMemsetAsync(counts, 0, NK * sizeof(int), stream);
  hist_k<<<NE / 256, blk, 0, stream>>>(dstp, etypep, counts);
  scan_block<<<(NK + 1023) / 1024, blk, 0, stream>>>(counts, offs, bsums);
  scan_bsums<<<1, blk, 0, stream>>>(bsums, (NK + 1023) / 1024);
  add_base<<<(NK + 1 + 255) / 256, blk, 0, stream>>>(offs, bsums);
  copy_int<<<(NK + 255) / 256, blk, 0, stream>>>(offs, cursor, NK);
  fill_k<<<NE / 256, blk, 0, stream>>>(srcp, dstp, etypep, cursor, ssrc);

  // ---- weight preprocessing ----
  transp_bf16<<<(HID * HID + 255) / 256, blk, 0, stream>>>(loop_w1, LWT1, HID, HID);
  transp_bf16<<<(HID * HID + 255) / 256, blk, 0, stream>>>(loop_w2, LWT2, HID, HID);
  transp_bf16<<<(KTIME * 128 + 255) / 256, blk, 0, stream>>>(time_w, TWT, KTIME, 128);

  // ---- input projections -> featb (N x 256 bf16) ----
  const int MG64 = (NN + 63) / 64;  // 313
  sgemm_bf<64, 64, 4, 4><<<dim3(MG64, 1), blk, 0, stream>>>(
      NN, 64, KPOI, poi_dist, KPOI, poi_w, 64, poi_b, featb + 0, HID);
  mfma_time<<<NN / 32, blk, 0, stream>>>(time_dist, TWT, time_b, featb);
  sgemm_bf<64, 64, 4, 4><<<dim3(MG64, 1), blk, 0, stream>>>(
      NN, 64, KROAD, road_feat, KROAD, road_w, 64, road_b, featb + 192, HID);

  // ---- layer 1 (fused aggregate + GEMM + bias + relu) ----
  make_WT<<<(NR * HID * HID + 255) / 256, blk, 0, stream>>>(coef1, basis1, WT);
  fused_layer<1><<<MG64, 512, 0, stream>>>(offs, ssrc, featb, WT, LWT1, bias1,
                                           h1b, nullptr);

  // ---- layer 2 ----
  make_WT<<<(NR * HID * HID + 255) / 256, blk, 0, stream>>>(coef2, basis2, WT);
  fused_layer<0><<<MG64, 512, 0, stream>>>(offs, ssrc, h1b, WT, LWT2, bias2,
                                           nullptr, out);
}

// Round 5
// 543.625 us; speedup vs baseline: 10.3489x; 1.0784x over previous
//
#include <hip/hip_runtime.h>

#define NN 20000
#define NE 640000
#define NR 8
#define NB 8
#define HID 256
#define KPOI 12
#define KTIME 2880
#define KROAD 128
#define NK (NN * NR)   // 160000 (dst,rel) keys

typedef __attribute__((ext_vector_type(8))) short bf8_t;   // 8 bf16 = 4 VGPR
typedef __attribute__((ext_vector_type(4))) float f4_t;

__device__ inline unsigned short f2bf(float f) {  // RNE f32->bf16
  unsigned int u = __float_as_uint(f);
  u += 0x7FFF + ((u >> 16) & 1);
  return (unsigned short)(u >> 16);
}
__device__ inline float bf2f(unsigned short h) {
  return __uint_as_float((unsigned int)h << 16);
}

// ---------------- WT[r][o][i] = sum_b coef[r,b]*basis[b][i][o]  (bf16) ------
__global__ __launch_bounds__(256) void make_WT(const float* __restrict__ coef,
                                               const float* __restrict__ basis,
                                               unsigned short* __restrict__ WT) {
  int idx = blockIdx.x * 256 + threadIdx.x;   // r*65536 + o*256 + i
  if (idx >= NR * HID * HID) return;
  int r = idx >> 16;
  int o = (idx >> 8) & 255;
  int i = idx & 255;
  float acc = 0.f;
#pragma unroll
  for (int b = 0; b < NB; ++b)
    acc += coef[r * NB + b] * basis[b * HID * HID + i * HID + o];
  WT[idx] = f2bf(acc);
}

// ---------------- transpose + convert: out[c][r] = in[r][c] (bf16) ---------
__global__ __launch_bounds__(256) void transp_bf16(const float* __restrict__ in,
                                                   unsigned short* __restrict__ out,
                                                   int R, int Cc) {
  int idx = blockIdx.x * 256 + threadIdx.x;
  if (idx >= R * Cc) return;
  int r = idx / Cc, c = idx - r * Cc;
  out[(size_t)c * R + r] = f2bf(in[idx]);
}

// ---------------- small f32 GEMM -> bf16 out (poi / road projections) ------
#define BK 16
template<int BM, int BN, int TM, int TN>
__global__ __launch_bounds__(256) void sgemm_bf(
    int M, int Nn, int K,
    const float* __restrict__ A, int lda,
    const float* __restrict__ B, int ldb,
    const float* __restrict__ bias,
    unsigned short* __restrict__ C, int ldc)
{
  constexpr int SA = BM + 4;
  constexpr int SB = BN + 4;
  __shared__ float As[BK * SA];
  __shared__ float Bs[BK * SB];
  const int tid = threadIdx.x;
  const int brow = blockIdx.x * BM;
  const int bcol = blockIdx.y * BN;
  constexpr int TCOLS = BN / TN;
  const int row0 = (tid / TCOLS) * TM;
  const int col0 = (tid % TCOLS) * TN;

  float acc[TM][TN] = {};

  for (int kb = 0; kb < K; kb += BK) {
    constexpr int AIT = (BM * 4) / 256;
#pragma unroll
    for (int it = 0; it < AIT; ++it) {
      int i = tid + it * 256;
      int r = i >> 2, q = (i & 3) * 4;
      int grow = brow + r, gk = kb + q;
      if (grow < M && gk + 3 < K) {
        float4 v = *(const float4*)(A + (size_t)grow * lda + gk);
        As[(q + 0) * SA + r] = v.x;
        As[(q + 1) * SA + r] = v.y;
        As[(q + 2) * SA + r] = v.z;
        As[(q + 3) * SA + r] = v.w;
      } else {
#pragma unroll
        for (int j = 0; j < 4; ++j)
          As[(q + j) * SA + r] =
              (grow < M && gk + j < K) ? A[(size_t)grow * lda + gk + j] : 0.f;
      }
    }
    constexpr int BIT = (BN * 4) / 256;
#pragma unroll
    for (int it = 0; it < BIT; ++it) {
      int i = tid + it * 256;
      int k = i / (BN / 4), cq = (i % (BN / 4)) * 4;
      int gk = kb + k, gc = bcol + cq;
      float4 v = {0.f, 0.f, 0.f, 0.f};
      if (gk < K) {
        if (gc + 3 < Nn) {
          v = *(const float4*)(B + (size_t)gk * ldb + gc);
        } else {
#pragma unroll
          for (int j = 0; j < 4; ++j)
            if (gc + j < Nn) (&v.x)[j] = B[(size_t)gk * ldb + gc + j];
        }
      }
      *(float4*)(&Bs[k * SB + cq]) = v;
    }
    __syncthreads();
#pragma unroll
    for (int kk = 0; kk < BK; ++kk) {
      float a[TM], b[TN];
#pragma unroll
      for (int i = 0; i < TM; i += 4)
        *(float4*)(&a[i]) = *(const float4*)(&As[kk * SA + row0 + i]);
#pragma unroll
      for (int j = 0; j < TN; j += 4)
        *(float4*)(&b[j]) = *(const float4*)(&Bs[kk * SB + col0 + j]);
#pragma unroll
      for (int i = 0; i < TM; ++i)
#pragma unroll
        for (int j = 0; j < TN; ++j)
          acc[i][j] += a[i] * b[j];
    }
    __syncthreads();
  }

  float bcache[TN];
#pragma unroll
  for (int j = 0; j < TN; ++j)
    bcache[j] = bias ? bias[bcol + col0 + j] : 0.f;
#pragma unroll
  for (int i = 0; i < TM; ++i) {
    int row = brow + row0 + i;
    if (row >= M) continue;
#pragma unroll
    for (int j = 0; j < TN; ++j) {
      int col = bcol + col0 + j;
      if (col < Nn)
        C[(size_t)row * ldc + col] = f2bf(acc[i][j] + bcache[j]);
    }
  }
}

// ---------------- time GEMM: featb[:,64:192] = time_dist @ TWT^T + b -------
__global__ __launch_bounds__(256) void mfma_time(
    const float* __restrict__ A,            // [NN][2880] f32
    const unsigned short* __restrict__ BT,  // [128][2880] bf16
    const float* __restrict__ bias,         // [128]
    unsigned short* __restrict__ featb)     // [NN][256]
{
  __shared__ __align__(16) char ldsA[32 * 128];
  __shared__ __align__(16) char ldsB[128 * 128];
  const int tid = threadIdx.x;
  const int lane = tid & 63;
  const int w = tid >> 6;            // 0..3 -> col block w*32
  const int brow = blockIdx.x * 32;

  f4_t acc[2][2];
#pragma unroll
  for (int i = 0; i < 2; ++i)
#pragma unroll
    for (int j = 0; j < 2; ++j) acc[i][j] = (f4_t){0.f, 0.f, 0.f, 0.f};

  for (int kb = 0; kb < KTIME; kb += 64) {
    {  // A: 32 rows x 64 k, f32 -> bf16
      int r = tid >> 3, c8 = tid & 7;
      const float* ap = A + (size_t)(brow + r) * KTIME + kb + c8 * 8;
      f4_t v0 = *(const f4_t*)ap;
      f4_t v1 = *(const f4_t*)(ap + 4);
      unsigned short hh[8];
#pragma unroll
      for (int j = 0; j < 4; ++j) { hh[j] = f2bf(v0[j]); hh[4 + j] = f2bf(v1[j]); }
      *(bf8_t*)(ldsA + r * 128 + ((c8 * 16) ^ ((r & 7) << 4))) = *(bf8_t*)hh;
    }
#pragma unroll
    for (int it = 0; it < 4; ++it) {  // B: 128 rows x 64 k
      int slot = tid + it * 256;
      int r = slot >> 3, c8 = slot & 7;
      bf8_t v = *(const bf8_t*)(BT + (size_t)r * KTIME + kb + c8 * 8);
      *(bf8_t*)(ldsB + r * 128 + ((c8 * 16) ^ ((r & 7) << 4))) = v;
    }
    __syncthreads();
#pragma unroll
    for (int ks = 0; ks < 2; ++ks) {
      const int kbyte = ks * 64 + (lane >> 4) * 16;
      bf8_t af[2], bfr[2];
#pragma unroll
      for (int mi = 0; mi < 2; ++mi) {
        int m = mi * 16 + (lane & 15);
        af[mi] = *(const bf8_t*)(ldsA + m * 128 + (kbyte ^ ((m & 7) << 4)));
      }
#pragma unroll
      for (int ni = 0; ni < 2; ++ni) {
        int n = w * 32 + ni * 16 + (lane & 15);
        bfr[ni] = *(const bf8_t*)(ldsB + n * 128 + (kbyte ^ ((n & 7) << 4)));
      }
#pragma unroll
      for (int mi = 0; mi < 2; ++mi)
#pragma unroll
        for (int ni = 0; ni < 2; ++ni)
          acc[mi][ni] = __builtin_amdgcn_mfma_f32_16x16x32_bf16(
              af[mi], bfr[ni], acc[mi][ni], 0, 0, 0);
    }
    __syncthreads();
  }

  const int rq = (lane >> 4) * 4;
  const int cl = lane & 15;
#pragma unroll
  for (int ni = 0; ni < 2; ++ni) {
    int c = w * 32 + ni * 16 + cl;
    float bv = bias[c];
#pragma unroll
    for (int mi = 0; mi < 2; ++mi) {
#pragma unroll
      for (int j = 0; j < 4; ++j) {
        int row = brow + mi * 16 + rq + j;
        featb[(size_t)row * 256 + 64 + c] = f2bf(acc[mi][ni][j] + bv);
      }
    }
  }
}

// ---------------- CSR segment aggregation into Z slices --------------------
// one wave per (slice q, dst d): Z[q*NN+d] = sum of hin[src] rows (bf16)
__global__ __launch_bounds__(256) void agg_k(
    const int* __restrict__ offs, const unsigned short* __restrict__ ssrc,
    const unsigned short* __restrict__ hin, unsigned short* __restrict__ Z,
    int rbase, int nseg) {
  int w = (blockIdx.x * 256 + threadIdx.x) >> 6;
  int lane = threadIdx.x & 63;
  if (w >= nseg) return;
  int q = w / NN;
  int d = w - q * NN;
  int r = rbase + q;
  int lo = offs[d * NR + r];
  int hi = offs[d * NR + r + 1];
  f4_t az = {0.f, 0.f, 0.f, 0.f};
  int e = lo;
  for (; e + 4 <= hi; e += 4) {
    int s0 = ssrc[e], s1 = ssrc[e + 1], s2 = ssrc[e + 2], s3 = ssrc[e + 3];
    ushort4 u0 = *(const ushort4*)(hin + (size_t)s0 * HID + lane * 4);
    ushort4 u1 = *(const ushort4*)(hin + (size_t)s1 * HID + lane * 4);
    ushort4 u2 = *(const ushort4*)(hin + (size_t)s2 * HID + lane * 4);
    ushort4 u3 = *(const ushort4*)(hin + (size_t)s3 * HID + lane * 4);
    az.x += (bf2f(u0.x) + bf2f(u1.x)) + (bf2f(u2.x) + bf2f(u3.x));
    az.y += (bf2f(u0.y) + bf2f(u1.y)) + (bf2f(u2.y) + bf2f(u3.y));
    az.z += (bf2f(u0.z) + bf2f(u1.z)) + (bf2f(u2.z) + bf2f(u3.z));
    az.w += (bf2f(u0.w) + bf2f(u1.w)) + (bf2f(u2.w) + bf2f(u3.w));
  }
  for (; e < hi; ++e) {
    int s = ssrc[e];
    ushort4 u = *(const ushort4*)(hin + (size_t)s * HID + lane * 4);
    az.x += bf2f(u.x); az.y += bf2f(u.y);
    az.z += bf2f(u.z); az.w += bf2f(u.w);
  }
  unsigned short hz[4] = {f2bf(az.x), f2bf(az.y), f2bf(az.z), f2bf(az.w)};
  *(ushort4*)(Z + (size_t)w * HID + lane * 4) = *(ushort4*)hz;
}

// ---------------- accumulation GEMM: C[64x256] (+)= sum_s A_s @ W_s^T ------
// block = 64 rows, 8 waves (512 thr). EPI: 0 = write bias+acc (f32)
//                                          1 = C += acc (f32)
//                                          2 = hb = bf16(relu(C + acc))
template<int NS, int EPI>
__global__ __launch_bounds__(512) void gemm_acc(
    const unsigned short* __restrict__ A0, const unsigned short* __restrict__ A1,
    const unsigned short* __restrict__ A2, const unsigned short* __restrict__ A3,
    const unsigned short* __restrict__ W0, const unsigned short* __restrict__ W1,
    const unsigned short* __restrict__ W2, const unsigned short* __restrict__ W3,
    const float* __restrict__ bias, float* __restrict__ C,
    unsigned short* __restrict__ hb)
{
  __shared__ __align__(16) char At[64 * 512];    // 32 KB: A tile, swizzled
  __shared__ __align__(16) char Bt[256 * 128];   // 32 KB: W chunk, swizzled
  const unsigned short* As[4] = {A0, A1, A2, A3};
  const unsigned short* Ws[4] = {W0, W1, W2, W3};
  const int tid = threadIdx.x;
  const int lane = tid & 63;
  const int w = tid >> 6;        // 0..7
  const int wr = w >> 1;         // rows wr*16..+15
  const int wc = w & 1;          // cols wc*128..+127
  const int brow = blockIdx.x * 64;

  f4_t acc[8];
#pragma unroll
  for (int i = 0; i < 8; ++i) acc[i] = (f4_t){0.f, 0.f, 0.f, 0.f};

#pragma unroll
  for (int s = 0; s < NS; ++s) {
    // ---- stage A tile: 64 rows x 256 bf16 (2048 slots of 16B) ----
#pragma unroll
    for (int it = 0; it < 4; ++it) {
      int slot = tid + it * 512;
      int r = slot >> 5, c16 = slot & 31;
      bf8_t v = {0, 0, 0, 0, 0, 0, 0, 0};
      int grow = brow + r;
      if (grow < NN) v = *(const bf8_t*)(As[s] + (size_t)grow * HID + c16 * 8);
      *(bf8_t*)(At + r * 512 + ((c16 * 16) ^ ((r & 7) << 4))) = v;
    }
    __syncthreads();
#pragma unroll
    for (int kc = 0; kc < 4; ++kc) {
#pragma unroll
      for (int it = 0; it < 4; ++it) {  // stage W chunk: 256 n-rows x 64 k
        int slot = tid + it * 512;
        int n = slot >> 3, c8 = slot & 7;
        bf8_t v = *(const bf8_t*)(Ws[s] + (size_t)n * HID + kc * 64 + c8 * 8);
        *(bf8_t*)(Bt + n * 128 + ((c8 * 16) ^ ((n & 7) << 4))) = v;
      }
      __syncthreads();
#pragma unroll
      for (int ks = 0; ks < 2; ++ks) {
        const int kbyte = ks * 64 + (lane >> 4) * 16;
        int m = wr * 16 + (lane & 15);
        bf8_t af = *(const bf8_t*)(
            At + m * 512 + ((kc * 128 + kbyte) ^ ((m & 7) << 4)));
#pragma unroll
        for (int ni = 0; ni < 8; ++ni) {
          int n = wc * 128 + ni * 16 + (lane & 15);
          bf8_t bfr = *(const bf8_t*)(Bt + n * 128 + (kbyte ^ ((n & 7) << 4)));
          acc[ni] = __builtin_amdgcn_mfma_f32_16x16x32_bf16(af, bfr, acc[ni], 0, 0, 0);
        }
      }
      __syncthreads();
    }
  }

  // ---- epilogue: D col = lane&15, row = (lane>>4)*4 + j ----
  const int rq = (lane >> 4) * 4;
  const int cl = lane & 15;
#pragma unroll
  for (int ni = 0; ni < 8; ++ni) {
    int c = wc * 128 + ni * 16 + cl;
    float bv = (EPI == 0) ? bias[c] : 0.f;
#pragma unroll
    for (int j = 0; j < 4; ++j) {
      int row = brow + wr * 16 + rq + j;
      if (row < NN) {
        size_t o = (size_t)row * 256 + c;
        if (EPI == 0) {
          C[o] = acc[ni][j] + bv;
        } else if (EPI == 1) {
          C[o] += acc[ni][j];
        } else {
          float v = C[o] + acc[ni][j];
          hb[o] = f2bf(fmaxf(v, 0.f));
        }
      }
    }
  }
}

// ---------------- CSR build: key = dst*NR + etype ----------------
__global__ __launch_bounds__(256) void hist_k(const int* __restrict__ dst,
                                              const int* __restrict__ et,
                                              int* __restrict__ counts) {
  int e = blockIdx.x * 256 + threadIdx.x;
  if (e < NE) atomicAdd(&counts[dst[e] * NR + et[e]], 1);
}

__global__ __launch_bounds__(256) void scan_block(const int* __restrict__ counts,
                                                  int* __restrict__ offs,
                                                  int* __restrict__ bsums) {
  __shared__ int sh[256];
  int base = blockIdx.x * 1024;
  int t = threadIdx.x;
  int v[4];
  int s = 0;
#pragma unroll
  for (int j = 0; j < 4; ++j) {
    int idx = base + t * 4 + j;
    v[j] = (idx < NK) ? counts[idx] : 0;
    s += v[j];
  }
  sh[t] = s;
  __syncthreads();
  for (int off = 1; off < 256; off <<= 1) {
    int x = (t >= off) ? sh[t - off] : 0;
    __syncthreads();
    sh[t] += x;
    __syncthreads();
  }
  int run = sh[t] - s;
#pragma unroll
  for (int j = 0; j < 4; ++j) {
    int idx = base + t * 4 + j;
    if (idx < NK) offs[idx] = run;
    run += v[j];
  }
  if (t == 255) bsums[blockIdx.x] = sh[255];
}

__global__ __launch_bounds__(256) void scan_bsums(int* __restrict__ bsums, int nblk) {
  __shared__ int sh[256];
  int t = threadIdx.x;
  int own = (t < nblk) ? bsums[t] : 0;
  sh[t] = own;
  __syncthreads();
  for (int off = 1; off < 256; off <<= 1) {
    int x = (t >= off) ? sh[t - off] : 0;
    __syncthreads();
    sh[t] += x;
    __syncthreads();
  }
  int ex = sh[t] - own;
  if (t < nblk) bsums[t] = ex;
}

__global__ __launch_bounds__(256) void add_base(int* __restrict__ offs,
                                                const int* __restrict__ bsums) {
  int idx = blockIdx.x * 256 + threadIdx.x;
  if (idx < NK) offs[idx] += bsums[idx >> 10];
  if (idx == NK) offs[NK] = NE;
}

__global__ __launch_bounds__(256) void copy_int(const int* __restrict__ a,
                                                int* __restrict__ b, int n) {
  int i = blockIdx.x * 256 + threadIdx.x;
  if (i < n) b[i] = a[i];
}

__global__ __launch_bounds__(256) void fill_k(const int* __restrict__ src,
                                              const int* __restrict__ dst,
                                              const int* __restrict__ et,
                                              int* __restrict__ cursor,
                                              unsigned short* __restrict__ ssrc) {
  int e = blockIdx.x * 256 + threadIdx.x;
  if (e < NE) {
    int key = dst[e] * NR + et[e];
    int p = atomicAdd(&cursor[key], 1);
    ssrc[p] = (unsigned short)src[e];
  }
}

extern "C" void kernel_launch(void* const* d_in, const int* in_sizes, int n_in,
                              void* d_out, int out_size, void* d_ws, size_t ws_size,
                              hipStream_t stream) {
  const int*   srcp      = (const int*)d_in[0];
  const int*   dstp      = (const int*)d_in[1];
  const int*   etypep    = (const int*)d_in[2];
  const float* poi_dist  = (const float*)d_in[3];
  const float* time_dist = (const float*)d_in[4];
  const float* road_feat = (const float*)d_in[5];
  const float* poi_w     = (const float*)d_in[6];
  const float* poi_b     = (const float*)d_in[7];
  const float* time_w    = (const float*)d_in[8];
  const float* time_b    = (const float*)d_in[9];
  const float* road_w    = (const float*)d_in[10];
  const float* road_b    = (const float*)d_in[11];
  const float* basis1    = (const float*)d_in[12];
  const float* coef1     = (const float*)d_in[13];
  const float* loop_w1   = (const float*)d_in[14];
  const float* bias1     = (const float*)d_in[15];
  const float* basis2    = (const float*)d_in[16];
  const float* coef2     = (const float*)d_in[17];
  const float* loop_w2   = (const float*)d_in[18];
  const float* bias2     = (const float*)d_in[19];

  float* out = (float*)d_out;

  // ws layout (bytes), total 44,929,040 (== proven round-3 budget):
  //   WT   bf16 @ 0          (1,048,576)   relation W^T, rebuilt L1->L2
  //   LWT1 bf16 @ 1,048,576  (131,072)
  //   LWT2 bf16 @ 1,179,648  (131,072)
  //   TWT  bf16 @ 1,310,720  (737,280)     time_w^T
  //   hbuf bf16 @ 2,048,000  (10,240,000)  featb in L1; relu(h1) bf16 in L2
  //   Z    bf16 @ 12,288,000 (30,720,000)  3 aggregation slices (N x 256 each)
  //   offs      @ 43,008,000 (640,016)
  //   bsums     @ 43,648,016 (1,024)
  //   ssrc u16  @ 43,649,040 (1,280,000)
  // h1 (f32, pre-relu) lives in d_out; dead before layer-2's first d_out write.
  // aliases: counts -> Z region, cursor -> hbuf region (both dead before
  // their host region's first real write).
  char* ws = (char*)d_ws;
  unsigned short* WT     = (unsigned short*)(ws);
  unsigned short* LWT1   = (unsigned short*)(ws + 1048576);
  unsigned short* LWT2   = (unsigned short*)(ws + 1179648);
  unsigned short* TWT    = (unsigned short*)(ws + 1310720);
  unsigned short* hbuf   = (unsigned short*)(ws + 2048000);
  unsigned short* Z      = (unsigned short*)(ws + 12288000);
  int*            offs   = (int*)  (ws + 43008000);
  int*            bsums  = (int*)  (ws + 43648016);
  unsigned short* ssrc   = (unsigned short*)(ws + 43649040);
  int*            counts = (int*)Z;
  int*            cursor = (int*)hbuf;

  unsigned short* Z0 = Z;
  unsigned short* Z1 = Z + (size_t)NN * HID;
  unsigned short* Z2 = Z + 2 * (size_t)NN * HID;
  auto WTr = [&](int r) { return WT + (size_t)r * HID * HID; };

  dim3 blk(256);
  const int MG64 = (NN + 63) / 64;        // 313
  const int AGG3 = (3 * NN + 3) / 4;      // 15000 blocks (4 waves each)
  const int AGG2 = (2 * NN + 3) / 4;      // 10000

  // ---- CSR build (aliases dead before hbuf/Z first writes) ----
  hipMemsetAsync(counts, 0, NK * sizeof(int), stream);
  hist_k<<<NE / 256, blk, 0, stream>>>(dstp, etypep, counts);
  scan_block<<<(NK + 1023) / 1024, blk, 0, stream>>>(counts, offs, bsums);
  scan_bsums<<<1, blk, 0, stream>>>(bsums, (NK + 1023) / 1024);
  add_base<<<(NK + 1 + 255) / 256, blk, 0, stream>>>(offs, bsums);
  copy_int<<<(NK + 255) / 256, blk, 0, stream>>>(offs, cursor, NK);
  fill_k<<<NE / 256, blk, 0, stream>>>(srcp, dstp, etypep, cursor, ssrc);

  // ---- weight preprocessing ----
  transp_bf16<<<(HID * HID + 255) / 256, blk, 0, stream>>>(loop_w1, LWT1, HID, HID);
  transp_bf16<<<(HID * HID + 255) / 256, blk, 0, stream>>>(loop_w2, LWT2, HID, HID);
  transp_bf16<<<(KTIME * 128 + 255) / 256, blk, 0, stream>>>(time_w, TWT, KTIME, 128);
  make_WT<<<(NR * HID * HID + 255) / 256, blk, 0, stream>>>(coef1, basis1, WT);

  // ---- input projections -> hbuf (N x 256 bf16) ----
  sgemm_bf<64, 64, 4, 4><<<dim3(MG64, 1), blk, 0, stream>>>(
      NN, 64, KPOI, poi_dist, KPOI, poi_w, 64, poi_b, hbuf + 0, HID);
  mfma_time<<<NN / 32, blk, 0, stream>>>(time_dist, TWT, time_b, hbuf);
  sgemm_bf<64, 64, 4, 4><<<dim3(MG64, 1), blk, 0, stream>>>(
      NN, 64, KROAD, road_feat, KROAD, road_w, 64, road_b, hbuf + 192, HID);

  // ---- layer 1: h1(f32, in d_out) = bias1 + self@LW1 + sum_r Z_r@W_r ----
  agg_k<<<AGG3, blk, 0, stream>>>(offs, ssrc, hbuf, Z, 0, 3 * NN);
  gemm_acc<4, 0><<<MG64, 512, 0, stream>>>(hbuf, Z0, Z1, Z2,
                                           LWT1, WTr(0), WTr(1), WTr(2),
                                           bias1, out, nullptr);
  agg_k<<<AGG3, blk, 0, stream>>>(offs, ssrc, hbuf, Z, 3, 3 * NN);
  gemm_acc<3, 1><<<MG64, 512, 0, stream>>>(Z0, Z1, Z2, nullptr,
                                           WTr(3), WTr(4), WTr(5), nullptr,
                                           nullptr, out, nullptr);
  agg_k<<<AGG2, blk, 0, stream>>>(offs, ssrc, hbuf, Z, 6, 2 * NN);
  // final pass: hbuf = bf16(relu(h1)) written in-place over featb (dead)
  gemm_acc<2, 2><<<MG64, 512, 0, stream>>>(Z0, Z1, nullptr, nullptr,
                                           WTr(6), WTr(7), nullptr, nullptr,
                                           nullptr, out, hbuf);

  // ---- layer 2: out(f32) = bias2 + self@LW2 + sum_r Z_r@W_r ----
  make_WT<<<(NR * HID * HID + 255) / 256, blk, 0, stream>>>(coef2, basis2, WT);
  agg_k<<<AGG3, blk, 0, stream>>>(offs, ssrc, hbuf, Z, 0, 3 * NN);
  gemm_acc<4, 0><<<MG64, 512, 0, stream>>>(hbuf, Z0, Z1, Z2,
                                           LWT2, WTr(0), WTr(1), WTr(2),
                                           bias2, out, nullptr);
  agg_k<<<AGG3, blk, 0, stream>>>(offs, ssrc, hbuf, Z, 3, 3 * NN);
  gemm_acc<3, 1><<<MG64, 512, 0, stream>>>(Z0, Z1, Z2, nullptr,
                                           WTr(3), WTr(4), WTr(5), nullptr,
                                           nullptr, out, nullptr);
  agg_k<<<AGG2, blk, 0, stream>>>(offs, ssrc, hbuf, Z, 6, 2 * NN);
  gemm_acc<2, 1><<<MG64, 512, 0, stream>>>(Z0, Z1, nullptr, nullptr,
                                           WTr(6), WTr(7), nullptr, nullptr,
                                           nullptr, out, nullptr);
}

// Round 6
// 459.766 us; speedup vs baseline: 12.2364x; 1.1824x over previous
//
#include <hip/hip_runtime.h>

#define NN 20000
#define NE 640000
#define NR 8
#define NB 8
#define HID 256
#define KPOI 12
#define KTIME 2880
#define KROAD 128
#define NK (NN * NR)   // 160000 (dst,rel) keys
#define SPLITK 5
#define KCH (KTIME / SPLITK)   // 576 = 9 x 64

typedef __attribute__((ext_vector_type(8))) short bf8_t;   // 8 bf16 = 4 VGPR
typedef __attribute__((ext_vector_type(4))) float f4_t;

__device__ inline unsigned short f2bf(float f) {  // RNE f32->bf16
  unsigned int u = __float_as_uint(f);
  u += 0x7FFF + ((u >> 16) & 1);
  return (unsigned short)(u >> 16);
}
__device__ inline float bf2f(unsigned short h) {
  return __uint_as_float((unsigned int)h << 16);
}

// ---------------- WT[r][o][i] = sum_b coef[r,b]*basis[b][i][o]  (bf16) ------
__global__ __launch_bounds__(256) void make_WT(const float* __restrict__ coef,
                                               const float* __restrict__ basis,
                                               unsigned short* __restrict__ WT) {
  int idx = blockIdx.x * 256 + threadIdx.x;   // r*65536 + o*256 + i
  if (idx >= NR * HID * HID) return;
  int r = idx >> 16;
  int o = (idx >> 8) & 255;
  int i = idx & 255;
  float acc = 0.f;
#pragma unroll
  for (int b = 0; b < NB; ++b)
    acc += coef[r * NB + b] * basis[b * HID * HID + i * HID + o];
  WT[idx] = f2bf(acc);
}

// ---------------- transpose + convert: out[c][r] = in[r][c] (bf16) ---------
__global__ __launch_bounds__(256) void transp_bf16(const float* __restrict__ in,
                                                   unsigned short* __restrict__ out,
                                                   int R, int Cc) {
  int idx = blockIdx.x * 256 + threadIdx.x;
  if (idx >= R * Cc) return;
  int r = idx / Cc, c = idx - r * Cc;
  out[(size_t)c * R + r] = f2bf(in[idx]);
}

// ---------------- small f32 GEMM -> bf16 out (poi / road projections) ------
#define BK 16
template<int BM, int BN, int TM, int TN>
__global__ __launch_bounds__(256) void sgemm_bf(
    int M, int Nn, int K,
    const float* __restrict__ A, int lda,
    const float* __restrict__ B, int ldb,
    const float* __restrict__ bias,
    unsigned short* __restrict__ C, int ldc)
{
  constexpr int SA = BM + 4;
  constexpr int SB = BN + 4;
  __shared__ float As[BK * SA];
  __shared__ float Bs[BK * SB];
  const int tid = threadIdx.x;
  const int brow = blockIdx.x * BM;
  const int bcol = blockIdx.y * BN;
  constexpr int TCOLS = BN / TN;
  const int row0 = (tid / TCOLS) * TM;
  const int col0 = (tid % TCOLS) * TN;

  float acc[TM][TN] = {};

  for (int kb = 0; kb < K; kb += BK) {
    constexpr int AIT = (BM * 4) / 256;
#pragma unroll
    for (int it = 0; it < AIT; ++it) {
      int i = tid + it * 256;
      int r = i >> 2, q = (i & 3) * 4;
      int grow = brow + r, gk = kb + q;
      if (grow < M && gk + 3 < K) {
        float4 v = *(const float4*)(A + (size_t)grow * lda + gk);
        As[(q + 0) * SA + r] = v.x;
        As[(q + 1) * SA + r] = v.y;
        As[(q + 2) * SA + r] = v.z;
        As[(q + 3) * SA + r] = v.w;
      } else {
#pragma unroll
        for (int j = 0; j < 4; ++j)
          As[(q + j) * SA + r] =
              (grow < M && gk + j < K) ? A[(size_t)grow * lda + gk + j] : 0.f;
      }
    }
    constexpr int BIT = (BN * 4) / 256;
#pragma unroll
    for (int it = 0; it < BIT; ++it) {
      int i = tid + it * 256;
      int k = i / (BN / 4), cq = (i % (BN / 4)) * 4;
      int gk = kb + k, gc = bcol + cq;
      float4 v = {0.f, 0.f, 0.f, 0.f};
      if (gk < K) {
        if (gc + 3 < Nn) {
          v = *(const float4*)(B + (size_t)gk * ldb + gc);
        } else {
#pragma unroll
          for (int j = 0; j < 4; ++j)
            if (gc + j < Nn) (&v.x)[j] = B[(size_t)gk * ldb + gc + j];
        }
      }
      *(float4*)(&Bs[k * SB + cq]) = v;
    }
    __syncthreads();
#pragma unroll
    for (int kk = 0; kk < BK; ++kk) {
      float a[TM], b[TN];
#pragma unroll
      for (int i = 0; i < TM; i += 4)
        *(float4*)(&a[i]) = *(const float4*)(&As[kk * SA + row0 + i]);
#pragma unroll
      for (int j = 0; j < TN; j += 4)
        *(float4*)(&b[j]) = *(const float4*)(&Bs[kk * SB + col0 + j]);
#pragma unroll
      for (int i = 0; i < TM; ++i)
#pragma unroll
        for (int j = 0; j < TN; ++j)
          acc[i][j] += a[i] * b[j];
    }
    __syncthreads();
  }

  float bcache[TN];
#pragma unroll
  for (int j = 0; j < TN; ++j)
    bcache[j] = bias ? bias[bcol + col0 + j] : 0.f;
#pragma unroll
  for (int i = 0; i < TM; ++i) {
    int row = brow + row0 + i;
    if (row >= M) continue;
#pragma unroll
    for (int j = 0; j < TN; ++j) {
      int col = bcol + col0 + j;
      if (col < Nn)
        C[(size_t)row * ldc + col] = f2bf(acc[i][j] + bcache[j]);
    }
  }
}

// ---------------- split-K time GEMM: TP[kc] = time_dist[:, kc-chunk] @ TWT^T
// grid (625, SPLITK); block 256 = 4 waves, each wave 32x32 of the 32x128 tile
__global__ __launch_bounds__(256) void mfma_time_sk(
    const float* __restrict__ A,            // [NN][2880] f32
    const unsigned short* __restrict__ BT,  // [128][2880] bf16
    float* __restrict__ TP)                 // [SPLITK][NN][128]
{
  __shared__ __align__(16) char ldsA[32 * 128];
  __shared__ __align__(16) char ldsB[128 * 128];
  const int tid = threadIdx.x;
  const int lane = tid & 63;
  const int w = tid >> 6;            // 0..3 -> col block w*32
  const int brow = blockIdx.x * 32;
  const int kb0 = blockIdx.y * KCH;

  f4_t acc[2][2];
#pragma unroll
  for (int i = 0; i < 2; ++i)
#pragma unroll
    for (int j = 0; j < 2; ++j) acc[i][j] = (f4_t){0.f, 0.f, 0.f, 0.f};

  for (int kb = kb0; kb < kb0 + KCH; kb += 64) {
    {  // A: 32 rows x 64 k, f32 -> bf16
      int r = tid >> 3, c8 = tid & 7;
      const float* ap = A + (size_t)(brow + r) * KTIME + kb + c8 * 8;
      f4_t v0 = *(const f4_t*)ap;
      f4_t v1 = *(const f4_t*)(ap + 4);
      unsigned short hh[8];
#pragma unroll
      for (int j = 0; j < 4; ++j) { hh[j] = f2bf(v0[j]); hh[4 + j] = f2bf(v1[j]); }
      *(bf8_t*)(ldsA + r * 128 + ((c8 * 16) ^ ((r & 7) << 4))) = *(bf8_t*)hh;
    }
#pragma unroll
    for (int it = 0; it < 4; ++it) {  // B: 128 rows x 64 k
      int slot = tid + it * 256;
      int r = slot >> 3, c8 = slot & 7;
      bf8_t v = *(const bf8_t*)(BT + (size_t)r * KTIME + kb + c8 * 8);
      *(bf8_t*)(ldsB + r * 128 + ((c8 * 16) ^ ((r & 7) << 4))) = v;
    }
    __syncthreads();
#pragma unroll
    for (int ks = 0; ks < 2; ++ks) {
      const int kbyte = ks * 64 + (lane >> 4) * 16;
      bf8_t af[2], bfr[2];
#pragma unroll
      for (int mi = 0; mi < 2; ++mi) {
        int m = mi * 16 + (lane & 15);
        af[mi] = *(const bf8_t*)(ldsA + m * 128 + (kbyte ^ ((m & 7) << 4)));
      }
#pragma unroll
      for (int ni = 0; ni < 2; ++ni) {
        int n = w * 32 + ni * 16 + (lane & 15);
        bfr[ni] = *(const bf8_t*)(ldsB + n * 128 + (kbyte ^ ((n & 7) << 4)));
      }
#pragma unroll
      for (int mi = 0; mi < 2; ++mi)
#pragma unroll
        for (int ni = 0; ni < 2; ++ni)
          acc[mi][ni] = __builtin_amdgcn_mfma_f32_16x16x32_bf16(
              af[mi], bfr[ni], acc[mi][ni], 0, 0, 0);
    }
    __syncthreads();
  }

  float* tp = TP + (size_t)blockIdx.y * NN * 128;
  const int rq = (lane >> 4) * 4;
  const int cl = lane & 15;
#pragma unroll
  for (int ni = 0; ni < 2; ++ni) {
    int c = w * 32 + ni * 16 + cl;
#pragma unroll
    for (int mi = 0; mi < 2; ++mi) {
#pragma unroll
      for (int j = 0; j < 4; ++j) {
        int row = brow + mi * 16 + rq + j;
        tp[(size_t)row * 128 + c] = acc[mi][ni][j];
      }
    }
  }
}

// ---------------- time finish: featb[:,64:192] = bf16(sum_k TP + bias) -----
__global__ __launch_bounds__(256) void time_finish(
    const float* __restrict__ TP, const float* __restrict__ bias,
    unsigned short* __restrict__ featb) {
  int i = blockIdx.x * 256 + threadIdx.x;   // over NN*32 float4 groups
  if (i >= NN * 32) return;
  int row = i >> 5, c4 = (i & 31) * 4;
  f4_t s = *(const f4_t*)(TP + (size_t)row * 128 + c4);
#pragma unroll
  for (int k = 1; k < SPLITK; ++k) {
    f4_t v = *(const f4_t*)(TP + (size_t)k * NN * 128 + (size_t)row * 128 + c4);
    s.x += v.x; s.y += v.y; s.z += v.z; s.w += v.w;
  }
  f4_t b = *(const f4_t*)(bias + c4);
  unsigned short h[4] = {f2bf(s.x + b.x), f2bf(s.y + b.y),
                         f2bf(s.z + b.z), f2bf(s.w + b.w)};
  *(ushort4*)(featb + (size_t)row * 256 + 64 + c4) = *(ushort4*)h;
}

// ---------------- CSR segment aggregation into Z slices --------------------
// one wave per (rel q, dst d): Z[q*NN+d] = sum of hin[src] rows (bf16)
__global__ __launch_bounds__(256) void agg_k(
    const int* __restrict__ offs, const unsigned short* __restrict__ ssrc,
    const unsigned short* __restrict__ hin, unsigned short* __restrict__ Z) {
  int w = (blockIdx.x * 256 + threadIdx.x) >> 6;
  int lane = threadIdx.x & 63;
  if (w >= NR * NN) return;
  int q = w / NN;
  int d = w - q * NN;
  int lo = offs[d * NR + q];
  int hi = offs[d * NR + q + 1];
  f4_t az = {0.f, 0.f, 0.f, 0.f};
  int e = lo;
  for (; e + 4 <= hi; e += 4) {
    int s0 = ssrc[e], s1 = ssrc[e + 1], s2 = ssrc[e + 2], s3 = ssrc[e + 3];
    ushort4 u0 = *(const ushort4*)(hin + (size_t)s0 * HID + lane * 4);
    ushort4 u1 = *(const ushort4*)(hin + (size_t)s1 * HID + lane * 4);
    ushort4 u2 = *(const ushort4*)(hin + (size_t)s2 * HID + lane * 4);
    ushort4 u3 = *(const ushort4*)(hin + (size_t)s3 * HID + lane * 4);
    az.x += (bf2f(u0.x) + bf2f(u1.x)) + (bf2f(u2.x) + bf2f(u3.x));
    az.y += (bf2f(u0.y) + bf2f(u1.y)) + (bf2f(u2.y) + bf2f(u3.y));
    az.z += (bf2f(u0.z) + bf2f(u1.z)) + (bf2f(u2.z) + bf2f(u3.z));
    az.w += (bf2f(u0.w) + bf2f(u1.w)) + (bf2f(u2.w) + bf2f(u3.w));
  }
  for (; e < hi; ++e) {
    int s = ssrc[e];
    ushort4 u = *(const ushort4*)(hin + (size_t)s * HID + lane * 4);
    az.x += bf2f(u.x); az.y += bf2f(u.y);
    az.z += bf2f(u.z); az.w += bf2f(u.w);
  }
  unsigned short hz[4] = {f2bf(az.x), f2bf(az.y), f2bf(az.z), f2bf(az.w)};
  *(ushort4*)(Z + (size_t)w * HID + lane * 4) = *(ushort4*)hz;
}

// ---------------- layer GEMM: acc = self@LWT + sum_r Z_r@W_r^T -------------
// block = 64 rows x 128 cols, 8 waves (512 thr); grid (313, 2)
// EPI 0: C = acc + bias (f32).  EPI 2: hb = bf16(relu(acc + bias)).
template<int EPI>
__global__ __launch_bounds__(512) void gemm_acc(
    const unsigned short* __restrict__ hbufA,  // self slice [NN][256]
    const unsigned short* __restrict__ Z,      // [NR][NN][256]
    const unsigned short* __restrict__ WT,     // [NR][256][256]
    const unsigned short* __restrict__ LWT,    // [256][256]
    const float* __restrict__ bias,
    float* __restrict__ C, unsigned short* __restrict__ hb)
{
  __shared__ __align__(16) char At[64 * 512];    // 32 KB, swizzled
  __shared__ __align__(16) char Bt[128 * 128];   // 16 KB, swizzled
  const int tid = threadIdx.x;
  const int lane = tid & 63;
  const int w = tid >> 6;        // 0..7
  const int wr = w >> 1;         // rows wr*16..+15
  const int wc = w & 1;          // cols (in block) wc*64..+63
  const int brow = blockIdx.x * 64;
  const int bcol = blockIdx.y * 128;

  f4_t acc[4];
#pragma unroll
  for (int i = 0; i < 4; ++i) acc[i] = (f4_t){0.f, 0.f, 0.f, 0.f};

#pragma unroll 1
  for (int s = 0; s < NR + 1; ++s) {
    const unsigned short* Asrc = (s == 0) ? hbufA : Z + (size_t)(s - 1) * NN * HID;
    const unsigned short* Wsrc = (s == 0) ? LWT : WT + (size_t)(s - 1) * HID * HID;
    // ---- stage A tile: 64 rows x 256 bf16 (2048 x 16B slots) ----
#pragma unroll
    for (int it = 0; it < 4; ++it) {
      int slot = tid + it * 512;
      int r = slot >> 5, c16 = slot & 31;
      bf8_t v = {0, 0, 0, 0, 0, 0, 0, 0};
      int grow = brow + r;
      if (grow < NN) v = *(const bf8_t*)(Asrc + (size_t)grow * HID + c16 * 8);
      *(bf8_t*)(At + r * 512 + ((c16 * 16) ^ ((r & 7) << 4))) = v;
    }
    __syncthreads();
#pragma unroll 1
    for (int kc = 0; kc < 4; ++kc) {
#pragma unroll
      for (int it = 0; it < 2; ++it) {  // stage W chunk: 128 n-rows x 64 k
        int slot = tid + it * 512;
        int n = slot >> 3, c8 = slot & 7;
        bf8_t v = *(const bf8_t*)(Wsrc + (size_t)(bcol + n) * HID + kc * 64 + c8 * 8);
        *(bf8_t*)(Bt + n * 128 + ((c8 * 16) ^ ((n & 7) << 4))) = v;
      }
      __syncthreads();
#pragma unroll
      for (int ks = 0; ks < 2; ++ks) {
        const int kbyte = ks * 64 + (lane >> 4) * 16;
        int m = wr * 16 + (lane & 15);
        bf8_t af = *(const bf8_t*)(
            At + m * 512 + ((kc * 128 + kbyte) ^ ((m & 7) << 4)));
#pragma unroll
        for (int ni = 0; ni < 4; ++ni) {
          int n = wc * 64 + ni * 16 + (lane & 15);
          bf8_t bfr = *(const bf8_t*)(Bt + n * 128 + (kbyte ^ ((n & 7) << 4)));
          acc[ni] = __builtin_amdgcn_mfma_f32_16x16x32_bf16(af, bfr, acc[ni], 0, 0, 0);
        }
      }
      __syncthreads();
    }
  }

  // ---- epilogue: D col = lane&15, row = (lane>>4)*4 + j ----
  const int rq = (lane >> 4) * 4;
  const int cl = lane & 15;
#pragma unroll
  for (int ni = 0; ni < 4; ++ni) {
    int c = bcol + wc * 64 + ni * 16 + cl;
    float bv = bias[c];
#pragma unroll
    for (int j = 0; j < 4; ++j) {
      int row = brow + wr * 16 + rq + j;
      if (row < NN) {
        size_t o = (size_t)row * 256 + c;
        float v = acc[ni][j] + bv;
        if (EPI == 0) C[o] = v;
        else          hb[o] = f2bf(fmaxf(v, 0.f));
      }
    }
  }
}

// ---------------- CSR build: key = dst*NR + etype ----------------
__global__ __launch_bounds__(256) void hist_k(const int* __restrict__ dst,
                                              const int* __restrict__ et,
                                              int* __restrict__ counts) {
  int e = blockIdx.x * 256 + threadIdx.x;
  if (e < NE) atomicAdd(&counts[dst[e] * NR + et[e]], 1);
}

__global__ __launch_bounds__(256) void scan_block(const int* __restrict__ counts,
                                                  int* __restrict__ offs,
                                                  int* __restrict__ bsums) {
  __shared__ int sh[256];
  int base = blockIdx.x * 1024;
  int t = threadIdx.x;
  int v[4];
  int s = 0;
#pragma unroll
  for (int j = 0; j < 4; ++j) {
    int idx = base + t * 4 + j;
    v[j] = (idx < NK) ? counts[idx] : 0;
    s += v[j];
  }
  sh[t] = s;
  __syncthreads();
  for (int off = 1; off < 256; off <<= 1) {
    int x = (t >= off) ? sh[t - off] : 0;
    __syncthreads();
    sh[t] += x;
    __syncthreads();
  }
  int run = sh[t] - s;
#pragma unroll
  for (int j = 0; j < 4; ++j) {
    int idx = base + t * 4 + j;
    if (idx < NK) offs[idx] = run;
    run += v[j];
  }
  if (t == 255) bsums[blockIdx.x] = sh[255];
}

__global__ __launch_bounds__(256) void scan_bsums(int* __restrict__ bsums, int nblk) {
  __shared__ int sh[256];
  int t = threadIdx.x;
  int own = (t < nblk) ? bsums[t] : 0;
  sh[t] = own;
  __syncthreads();
  for (int off = 1; off < 256; off <<= 1) {
    int x = (t >= off) ? sh[t - off] : 0;
    __syncthreads();
    sh[t] += x;
    __syncthreads();
  }
  int ex = sh[t] - own;
  if (t < nblk) bsums[t] = ex;
}

__global__ __launch_bounds__(256) void add_base(int* __restrict__ offs,
                                                const int* __restrict__ bsums) {
  int idx = blockIdx.x * 256 + threadIdx.x;
  if (idx < NK) offs[idx] += bsums[idx >> 10];
  if (idx == NK) offs[NK] = NE;
}

__global__ __launch_bounds__(256) void copy_int(const int* __restrict__ a,
                                                int* __restrict__ b, int n) {
  int i = blockIdx.x * 256 + threadIdx.x;
  if (i < n) b[i] = a[i];
}

__global__ __launch_bounds__(256) void fill_k(const int* __restrict__ src,
                                              const int* __restrict__ dst,
                                              const int* __restrict__ et,
                                              int* __restrict__ cursor,
                                              unsigned short* __restrict__ ssrc) {
  int e = blockIdx.x * 256 + threadIdx.x;
  if (e < NE) {
    int key = dst[e] * NR + et[e];
    int p = atomicAdd(&cursor[key], 1);
    ssrc[p] = (unsigned short)src[e];
  }
}

extern "C" void kernel_launch(void* const* d_in, const int* in_sizes, int n_in,
                              void* d_out, int out_size, void* d_ws, size_t ws_size,
                              hipStream_t stream) {
  const int*   srcp      = (const int*)d_in[0];
  const int*   dstp      = (const int*)d_in[1];
  const int*   etypep    = (const int*)d_in[2];
  const float* poi_dist  = (const float*)d_in[3];
  const float* time_dist = (const float*)d_in[4];
  const float* road_feat = (const float*)d_in[5];
  const float* poi_w     = (const float*)d_in[6];
  const float* poi_b     = (const float*)d_in[7];
  const float* time_w    = (const float*)d_in[8];
  const float* time_b    = (const float*)d_in[9];
  const float* road_w    = (const float*)d_in[10];
  const float* road_b    = (const float*)d_in[11];
  const float* basis1    = (const float*)d_in[12];
  const float* coef1     = (const float*)d_in[13];
  const float* loop_w1   = (const float*)d_in[14];
  const float* bias1     = (const float*)d_in[15];
  const float* basis2    = (const float*)d_in[16];
  const float* coef2     = (const float*)d_in[17];
  const float* loop_w2   = (const float*)d_in[18];
  const float* bias2     = (const float*)d_in[19];

  float* out = (float*)d_out;

  // ws layout (bytes), total ~147.3 MB (ws_size ~921 MB per harness poison):
  //   WT   bf16 @ 0           (1,048,576)   relation W^T, rebuilt L1->L2
  //   LWT1 bf16 @ 1,048,576   (131,072)
  //   LWT2 bf16 @ 1,179,648   (131,072)
  //   TWT  bf16 @ 1,310,720   (737,280)     time_w^T
  //   hbuf bf16 @ 2,048,000   (10,240,000)  featb in L1; relu(h1) bf16 in L2
  //   Z    bf16 @ 12,288,000  (81,920,000)  8 slices (N x 256 each)
  //   TP   f32  @ 94,208,000  (51,200,000)  split-K time partials
  //   offs      @ 145,408,000 (640,016)
  //   bsums     @ 146,048,016 (1,024)
  //   ssrc u16  @ 146,049,040 (1,280,000)
  // aliases (dead before host region's first real write):
  //   counts -> Z region, cursor -> TP region
  char* ws = (char*)d_ws;
  unsigned short* WT     = (unsigned short*)(ws);
  unsigned short* LWT1   = (unsigned short*)(ws + 1048576);
  unsigned short* LWT2   = (unsigned short*)(ws + 1179648);
  unsigned short* TWT    = (unsigned short*)(ws + 1310720);
  unsigned short* hbuf   = (unsigned short*)(ws + 2048000);
  unsigned short* Z      = (unsigned short*)(ws + 12288000);
  float*          TP     = (float*)(ws + 94208000);
  int*            offs   = (int*)  (ws + 145408000);
  int*            bsums  = (int*)  (ws + 146048016);
  unsigned short* ssrc   = (unsigned short*)(ws + 146049040);
  int*            counts = (int*)Z;
  int*            cursor = (int*)TP;

  dim3 blk(256);
  const int MG64 = (NN + 63) / 64;  // 313

  // ---- CSR build (aliases dead before Z/TP first writes) ----
  hipMemsetAsync(counts, 0, NK * sizeof(int), stream);
  hist_k<<<NE / 256, blk, 0, stream>>>(dstp, etypep, counts);
  scan_block<<<(NK + 1023) / 1024, blk, 0, stream>>>(counts, offs, bsums);
  scan_bsums<<<1, blk, 0, stream>>>(bsums, (NK + 1023) / 1024);
  add_base<<<(NK + 1 + 255) / 256, blk, 0, stream>>>(offs, bsums);
  copy_int<<<(NK + 255) / 256, blk, 0, stream>>>(offs, cursor, NK);
  fill_k<<<NE / 256, blk, 0, stream>>>(srcp, dstp, etypep, cursor, ssrc);

  // ---- weight preprocessing ----
  transp_bf16<<<(HID * HID + 255) / 256, blk, 0, stream>>>(loop_w1, LWT1, HID, HID);
  transp_bf16<<<(HID * HID + 255) / 256, blk, 0, stream>>>(loop_w2, LWT2, HID, HID);
  transp_bf16<<<(KTIME * 128 + 255) / 256, blk, 0, stream>>>(time_w, TWT, KTIME, 128);
  make_WT<<<(NR * HID * HID + 255) / 256, blk, 0, stream>>>(coef1, basis1, WT);

  // ---- input projections -> hbuf (N x 256 bf16) ----
  sgemm_bf<64, 64, 4, 4><<<dim3(MG64, 1), blk, 0, stream>>>(
      NN, 64, KPOI, poi_dist, KPOI, poi_w, 64, poi_b, hbuf + 0, HID);
  mfma_time_sk<<<dim3(NN / 32, SPLITK), blk, 0, stream>>>(time_dist, TWT, TP);
  time_finish<<<(NN * 32 + 255) / 256, blk, 0, stream>>>(TP, time_b, hbuf);
  sgemm_bf<64, 64, 4, 4><<<dim3(MG64, 1), blk, 0, stream>>>(
      NN, 64, KROAD, road_feat, KROAD, road_w, 64, road_b, hbuf + 192, HID);

  // ---- layer 1: hbuf = bf16(relu(bias1 + self@LW1 + sum_r Z_r@W_r)) ----
  agg_k<<<(NR * NN) / 4, blk, 0, stream>>>(offs, ssrc, hbuf, Z);
  gemm_acc<2><<<dim3(MG64, 2), 512, 0, stream>>>(hbuf, Z, WT, LWT1, bias1,
                                                 nullptr, hbuf);

  // ---- layer 2: out = bias2 + self@LW2 + sum_r Z_r@W_r (f32) ----
  make_WT<<<(NR * HID * HID + 255) / 256, blk, 0, stream>>>(coef2, basis2, WT);
  agg_k<<<(NR * NN) / 4, blk, 0, stream>>>(offs, ssrc, hbuf, Z);
  gemm_acc<0><<<dim3(MG64, 2), 512, 0, stream>>>(hbuf, Z, WT, LWT2, bias2,
                                                 out, nullptr);
}